// Round 1
// baseline (13649.257 us; speedup 1.0000x reference)
//
#include <hip/hip_runtime.h>
#include <hip/hip_bf16.h>

// ---------------------------------------------------------------------------
// Problem constants
// ---------------------------------------------------------------------------
#define NB    128      // batch / trees
#define HD    100      // hidden / feature dim
#define NU    20000    // users
#define NTG   10000    // graph tweet nodes
#define NTREE 30000    // tree nodes
#define NG    30000    // graph-GAT node count (NTG + NU)
#define TT    20       // seq len
#define EG    200000   // graph edges
#define ET    60000    // tree edges

#define ACT_NONE 0
#define ACT_RELU 1

// ---------------------------------------------------------------------------
// Generic tiled GEMM:  C[m][n] = sum_k A[row(m)][k] * W[n][k] (+bias) (+relu)
// A: [M][K] rows optionally indirected through gather[m*gstride+goff]
// Tile: 64 rows x 128 cols, KC=20. blockIdx.z selects one of two GEMM sets
// (used to batch the GRU's x-side and h-side gate GEMMs in one launch).
// ---------------------------------------------------------------------------
__global__ __launch_bounds__(256) void gemm_nt(
    const float* __restrict__ A0, const float* __restrict__ A1,
    const float* __restrict__ W0, const float* __restrict__ W1,
    const float* __restrict__ b0, const float* __restrict__ b1,
    float* __restrict__ C0, float* __restrict__ C1,
    const int* __restrict__ gather, int gstride, int goff,
    int M, int N, int K, int act)
{
    const int z = blockIdx.z;
    const float* __restrict__ A    = z ? A1 : A0;
    const float* __restrict__ W    = z ? W1 : W0;
    const float* __restrict__ bias = z ? b1 : b0;
    float* __restrict__ C          = z ? C1 : C0;
    const int* __restrict__ gi     = z ? nullptr : gather;

    __shared__ float As[20][68];    // stride 68: 16B-aligned rows, few conflicts
    __shared__ float Ws[20][132];

    const int tid = threadIdx.x;
    const int m0 = blockIdx.x * 64;
    const int n0 = blockIdx.y * 128;
    const int r0 = (tid >> 4) * 4;      // 16 row-groups of 4
    const int c0 = (tid & 15) * 8;      // 16 col-groups of 8

    float acc[4][8];
#pragma unroll
    for (int i = 0; i < 4; ++i)
#pragma unroll
        for (int j = 0; j < 8; ++j) acc[i][j] = 0.f;

    const int nch = (K + 19) / 20;
    for (int ch = 0; ch < nch; ++ch) {
        const int k0 = ch * 20;
        // stage A tile (64x20), coalesced runs of 20 along k
#pragma unroll
        for (int it = 0; it < 5; ++it) {
            int idx = tid + it * 256;           // < 1280
            int r = idx / 20, kk = idx - r * 20;
            int m = m0 + r, k = k0 + kk;
            float v = 0.f;
            if (m < M && k < K) {
                int row = gi ? gi[m * gstride + goff] : m;
                v = A[row * K + k];
            }
            As[kk][r] = v;
        }
        // stage W tile (128x20)
#pragma unroll
        for (int it = 0; it < 10; ++it) {
            int idx = tid + it * 256;           // < 2560
            int j = idx / 20, kk = idx - j * 20;
            int n = n0 + j, k = k0 + kk;
            float v = 0.f;
            if (n < N && k < K) v = W[n * K + k];
            Ws[kk][j] = v;
        }
        __syncthreads();
#pragma unroll
        for (int kk = 0; kk < 20; ++kk) {
            float4 a   = *(const float4*)&As[kk][r0];
            float4 wA  = *(const float4*)&Ws[kk][c0];
            float4 wB  = *(const float4*)&Ws[kk][c0 + 4];
            float av[4] = {a.x, a.y, a.z, a.w};
            float wv[8] = {wA.x, wA.y, wA.z, wA.w, wB.x, wB.y, wB.z, wB.w};
#pragma unroll
            for (int i = 0; i < 4; ++i)
#pragma unroll
                for (int j = 0; j < 8; ++j)
                    acc[i][j] = fmaf(av[i], wv[j], acc[i][j]);
        }
        __syncthreads();
    }
#pragma unroll
    for (int i = 0; i < 4; ++i) {
        int m = m0 + r0 + i;
        if (m >= M) continue;
#pragma unroll
        for (int j = 0; j < 8; ++j) {
            int n = n0 + c0 + j;
            if (n >= N) continue;
            float v = acc[i][j];
            if (bias) v += bias[n];
            if (act == ACT_RELU) v = fmaxf(v, 0.f);
            C[m * N + n] = v;
        }
    }
}

// ---------------------------------------------------------------------------
// GRU gate combine: h = (1-z)*tanh(in + r*hn) + z*h    (in-place h update)
// Gx = x@Wih.T + bih   Gh = h@Whh.T + bhh   (each [N][300])
// ---------------------------------------------------------------------------
__global__ void gru_combine(const float* __restrict__ Gx, const float* __restrict__ Gh,
                            float* __restrict__ h, int N)
{
    int tid = blockIdx.x * blockDim.x + threadIdx.x;
    if (tid >= N * HD) return;
    int n = tid / HD, c = tid - n * HD;
    const float* gx = Gx + n * 300;
    const float* gh = Gh + n * 300;
    float r  = 1.f / (1.f + __expf(-(gx[c]       + gh[c])));
    float zz = 1.f / (1.f + __expf(-(gx[100 + c] + gh[100 + c])));
    float ng = tanhf(gx[200 + c] + r * gh[200 + c]);
    float hv = h[tid];
    h[tid] = (1.f - zz) * ng + zz * hv;
}

// xg = concat(hg[:128], ue, hg[128:])
__global__ void build_xg(const float* __restrict__ hg, const float* __restrict__ ue,
                         float* __restrict__ xg)
{
    int tid = blockIdx.x * blockDim.x + threadIdx.x;
    if (tid >= NG * HD) return;
    int n = tid / HD, c = tid - n * HD;
    float v;
    if (n < NB)              v = hg[n * HD + c];
    else if (n < NB + NU)    v = ue[(n - NB) * HD + c];
    else                     v = hg[(n - NU) * HD + c];
    xg[tid] = v;
}

__global__ void copy_block(const float* __restrict__ src, float* __restrict__ dst, int n)
{
    int t = blockIdx.x * blockDim.x + threadIdx.x;
    if (t < n) dst[t] = src[t];
}

// per-(node,head) attention logits pieces: es = <h, a_src>, ed = <h, a_dst>
__global__ void gat_es_ed(const float* __restrict__ feat, const float* __restrict__ asrc,
                          const float* __restrict__ adst, float* __restrict__ es,
                          float* __restrict__ ed, int N, int heads, int C)
{
    int gid = blockIdx.x * blockDim.x + threadIdx.x;
    if (gid >= N * heads) return;
    int n = gid / heads, hd = gid - n * heads;
    const float* hp = feat + (n * heads + hd) * C;
    const float* as = asrc + hd * C;
    const float* ad = adst + hd * C;
    float s1 = 0.f, s2 = 0.f;
    for (int c = 0; c < C; ++c) { float v = hp[c]; s1 += v * as[c]; s2 += v * ad[c]; }
    es[gid] = s1; ed[gid] = s2;
}

__device__ __forceinline__ void atomic_max_f(float* addr, float v)
{
    if (v >= 0.f) atomicMax((int*)addr, __float_as_int(v));
    else          atomicMin((unsigned int*)addr, __float_as_uint(v));
}

// leaky_relu logit per (edge,head); store; segment-max into m[dst]
__global__ void gat_edge_logit(const int* __restrict__ ei, int E, int N, int heads,
                               const float* __restrict__ es, const float* __restrict__ ed,
                               float* __restrict__ eb, float* __restrict__ m)
{
    int gid = blockIdx.x * blockDim.x + threadIdx.x;
    int EE = E + N;
    if (gid >= EE * heads) return;
    int idx = gid / heads, hd = gid - idx * heads;
    int src, dst;
    if (idx < E) { src = ei[idx]; dst = ei[E + idx]; } else { src = dst = idx - E; }
    float e = es[src * heads + hd] + ed[dst * heads + hd];
    e = e > 0.f ? e : 0.2f * e;
    eb[gid] = e;
    atomic_max_f(&m[dst * heads + hd], e);
}

// ee = exp(e - m[dst]); segment-sum into s[dst]
__global__ void gat_edge_expsum(const int* __restrict__ ei, int E, int N, int heads,
                                float* __restrict__ eb, const float* __restrict__ m,
                                float* __restrict__ s)
{
    int gid = blockIdx.x * blockDim.x + threadIdx.x;
    int EE = E + N;
    if (gid >= EE * heads) return;
    int idx = gid / heads, hd = gid - idx * heads;
    int dst = (idx < E) ? ei[E + idx] : idx - E;
    float e = __expf(eb[gid] - m[dst * heads + hd]);
    eb[gid] = e;
    atomicAdd(&s[dst * heads + hd], e);
}

// out[dst] += alpha * h[src]  (one block per edge, one thread per feature)
__global__ void gat_edge_accum(const int* __restrict__ ei, int E, int N, int heads,
                               int C, int HC,
                               const float* __restrict__ eb, const float* __restrict__ s,
                               const float* __restrict__ feat, float* __restrict__ accum)
{
    int e = blockIdx.x;
    int t = threadIdx.x;
    if (t >= HC) return;
    int src, dst;
    if (e < E) { src = ei[e]; dst = ei[E + e]; } else { src = dst = e - E; }
    int hd = t / C;
    float alpha = eb[e * heads + hd] / s[dst * heads + hd];
    atomicAdd(&accum[dst * HC + t], feat[src * HC + t] * alpha);
}

__global__ void gat_bias_relu(float* __restrict__ x, const float* __restrict__ bias,
                              int total, int HC)
{
    int t = blockIdx.x * blockDim.x + threadIdx.x;
    if (t >= total) return;
    int c = t % HC;
    x[t] = fmaxf(x[t] + bias[c], 0.f);
}

__global__ void scatter_mean_accum(const float* __restrict__ x, const int* __restrict__ idx,
                                   float* __restrict__ ssum, float* __restrict__ cnt)
{
    int t = blockIdx.x * blockDim.x + threadIdx.x;
    if (t >= NTREE * HD) return;
    int n = t / HD, c = t - n * HD;
    int b = idx[n];
    atomicAdd(&ssum[b * HD + c], x[t]);
    if (c == 0) atomicAdd(&cnt[b], 1.f);
}

__global__ void fc_out(const float* __restrict__ ssum, const float* __restrict__ cnt,
                       const float* __restrict__ W, const float* __restrict__ b,
                       float* __restrict__ out)
{
    int t = threadIdx.x;                 // 512 threads
    int bb = t >> 2, j = t & 3;
    float inv = 1.f / fmaxf(cnt[bb], 1.f);
    float acc = b[j];
    for (int k = 0; k < HD; ++k) acc += ssum[bb * HD + k] * inv * W[j * HD + k];
    out[t] = acc;
}

// ---------------------------------------------------------------------------
// Host launcher
// ---------------------------------------------------------------------------
extern "C" void kernel_launch(void* const* d_in, const int* in_sizes, int n_in,
                              void* d_out, int out_size, void* d_ws, size_t ws_size,
                              hipStream_t stream)
{
    // ---- inputs (setup_inputs dict order) ----
    const float* user_feats = (const float*)d_in[1];
    const int*   gnf        = (const int*)d_in[2];
    const int*   gei        = (const int*)d_in[3];
    const int*   tnf        = (const int*)d_in[4];
    const int*   tei        = (const int*)d_in[5];
    const int*   indices    = (const int*)d_in[6];
    const float* h0g        = (const float*)d_in[7];
    const float* h0t        = (const float*)d_in[8];
    const float* temb       = (const float*)d_in[9];
    const float* gW[2][4] = {{(const float*)d_in[10], (const float*)d_in[11], (const float*)d_in[12], (const float*)d_in[13]},
                             {(const float*)d_in[14], (const float*)d_in[15], (const float*)d_in[16], (const float*)d_in[17]}};
    const float* tW[2][4] = {{(const float*)d_in[18], (const float*)d_in[19], (const float*)d_in[20], (const float*)d_in[21]},
                             {(const float*)d_in[22], (const float*)d_in[23], (const float*)d_in[24], (const float*)d_in[25]}};
    const float* uW1 = (const float*)d_in[26]; const float* ub1 = (const float*)d_in[27];
    const float* uW2 = (const float*)d_in[28]; const float* ub2 = (const float*)d_in[29];
    const float* gc1W = (const float*)d_in[30]; const float* gc1as = (const float*)d_in[31];
    const float* gc1ad = (const float*)d_in[32]; const float* gc1b = (const float*)d_in[33];
    const float* gc2W = (const float*)d_in[34]; const float* gc2as = (const float*)d_in[35];
    const float* gc2ad = (const float*)d_in[36]; const float* gc2b = (const float*)d_in[37];
    const float* tc1W = (const float*)d_in[38]; const float* tc1as = (const float*)d_in[39];
    const float* tc1ad = (const float*)d_in[40]; const float* tc1b = (const float*)d_in[41];
    const float* tc2W = (const float*)d_in[42]; const float* tc2as = (const float*)d_in[43];
    const float* tc2ad = (const float*)d_in[44]; const float* tc2b = (const float*)d_in[45];
    const float* fcW = (const float*)d_in[46]; const float* fcb = (const float*)d_in[47];
    float* out = (float*)d_out;

    // ---- workspace layout (bytes) ----
    const size_t OFF_A  = 0;          // 12 MB  (h layer0 / xg)
    const size_t OFF_B  = 12000000;   // 12 MB  (h layer1 / xt)
    const size_t OFF_G  = 24000000;   // 96 MB  (ue / feat / xg_final@+48MB)
    const size_t OFF_H  = 120000000;  // 96 MB  (GRU gates / GAT accum / hid)
    const size_t OFF_ES = 216000000;
    const size_t OFF_ED = 216960000;
    const size_t OFF_M  = 217920000;
    const size_t OFF_S  = 218880000;
    const size_t OFF_EB = 219840000;  // 7.36 MB
    const size_t OFF_SS = 227201024;
    const size_t OFF_CNT= 227252224;
    const size_t NEED   = 227252736;
    if (ws_size < NEED) return;   // visible failure rather than OOB

    char* ws = (char*)d_ws;
    float* bufA  = (float*)(ws + OFF_A);
    float* bufB  = (float*)(ws + OFF_B);
    float* bufG  = (float*)(ws + OFF_G);
    float* bufH  = (float*)(ws + OFF_H);
    float* esb   = (float*)(ws + OFF_ES);
    float* edb   = (float*)(ws + OFF_ED);
    float* mb    = (float*)(ws + OFF_M);
    float* sb    = (float*)(ws + OFF_S);
    float* eb    = (float*)(ws + OFF_EB);
    float* ssum  = (float*)(ws + OFF_SS);
    float* cnt   = (float*)(ws + OFF_CNT);
    float* xgfin = bufG + 12000000;   // G + 48 MB (floats)
    float* Gx    = bufH;
    float* Gh    = bufH + 9000000;    // H + 36 MB

    auto gemm = [&](const float* A, const float* W, const float* bias, float* C,
                    int M, int N, int K, int act,
                    const int* gather = nullptr, int gs = 0, int go = 0) {
        dim3 grid((M + 63) / 64, (N + 127) / 128, 1);
        gemm_nt<<<grid, 256, 0, stream>>>(A, nullptr, W, nullptr, bias, nullptr,
                                          C, nullptr, gather, gs, go, M, N, K, act);
    };
    auto gemm2 = [&](const float* A0, const int* gather, int gs, int go,
                     const float* W0, const float* b0, float* C0,
                     const float* A1, const float* W1, const float* b1, float* C1,
                     int M, int N, int K) {
        dim3 grid((M + 63) / 64, (N + 127) / 128, 2);
        gemm_nt<<<grid, 256, 0, stream>>>(A0, A1, W0, W1, b0, b1, C0, C1,
                                          gather, gs, go, M, N, K, ACT_NONE);
    };
    auto gat = [&](const float* x, int N, int K, int heads, int C,
                   const float* W, const float* asrc, const float* adst, const float* bias,
                   const int* ei, int E, float* feat, float* accum) {
        int HC = heads * C;
        int EE = E + N;
        gemm(x, W, nullptr, feat, N, HC, K, ACT_NONE);
        gat_es_ed<<<(N * heads + 255) / 256, 256, 0, stream>>>(feat, asrc, adst, esb, edb, N, heads, C);
        hipMemsetAsync(mb, 0xFF, (size_t)N * heads * 4, stream);
        hipMemsetAsync(sb, 0, (size_t)N * heads * 4, stream);
        gat_edge_logit<<<(EE * heads + 255) / 256, 256, 0, stream>>>(ei, E, N, heads, esb, edb, eb, mb);
        gat_edge_expsum<<<(EE * heads + 255) / 256, 256, 0, stream>>>(ei, E, N, heads, eb, mb, sb);
        hipMemsetAsync(accum, 0, (size_t)N * HC * 4, stream);
        int bt = ((HC + 63) / 64) * 64;
        gat_edge_accum<<<EE, bt, 0, stream>>>(ei, E, N, heads, C, HC, eb, sb, feat, accum);
        gat_bias_relu<<<((size_t)N * HC + 255) / 256, 256, 0, stream>>>(accum, bias, N * HC, HC);
    };

    // ---- 1. user embed: ue = relu(uf@uW1.T+ub1)@uW2.T+ub2 ----
    float* hid = bufH;                 // 20000x100 (dead before GRU gates)
    float* ue  = bufG;                 // 20000x100
    gemm(user_feats, uW1, ub1, hid, NU, HD, 9, ACT_RELU);
    gemm(hid, uW2, ub2, ue, NU, HD, HD, ACT_NONE);

    // ---- 2. graph GRU (2 layers, interleaved per step) ----
    hipMemcpyAsync(bufA, h0g,                (size_t)NTG * HD * 4, hipMemcpyDeviceToDevice, stream);
    hipMemcpyAsync(bufB, h0g + NTG * HD,     (size_t)NTG * HD * 4, hipMemcpyDeviceToDevice, stream);
    for (int t = 0; t < TT; ++t) {
        gemm2(temb, gnf, TT, t, gW[0][0], gW[0][2], Gx,
              bufA, gW[0][1], gW[0][3], Gh, NTG, 300, HD);
        gru_combine<<<(NTG * HD + 255) / 256, 256, 0, stream>>>(Gx, Gh, bufA, NTG);
        gemm2(bufA, nullptr, 0, 0, gW[1][0], gW[1][2], Gx,
              bufB, gW[1][1], gW[1][3], Gh, NTG, 300, HD);
        gru_combine<<<(NTG * HD + 255) / 256, 256, 0, stream>>>(Gx, Gh, bufB, NTG);
    }

    // ---- 3. xg = concat(hg[:128], ue, hg[128:]) ----
    build_xg<<<(NG * HD + 255) / 256, 256, 0, stream>>>(bufB, ue, bufA);  // xg -> bufA

    // ---- 4. graph GAT1 (8 heads x 64, K=100), out in-place in bufH ----
    gat(bufA, NG, HD, 8, 64, gc1W, gc1as, gc1ad, gc1b, gei, EG, bufG, bufH);
    // ---- 5. graph GAT2 (1 head x 100, K=512) -> xg_final at G+48MB ----
    gat(bufH, NG, 512, 1, 100, gc2W, gc2as, gc2ad, gc2b, gei, EG, bufG, xgfin);

    // ---- 6. tree GRU ----
    hipMemcpyAsync(bufA, h0t,                  (size_t)NTREE * HD * 4, hipMemcpyDeviceToDevice, stream);
    hipMemcpyAsync(bufB, h0t + NTREE * HD,     (size_t)NTREE * HD * 4, hipMemcpyDeviceToDevice, stream);
    for (int t = 0; t < TT; ++t) {
        gemm2(temb, tnf, TT, t, tW[0][0], tW[0][2], Gx,
              bufA, tW[0][1], tW[0][3], Gh, NTREE, 300, HD);
        gru_combine<<<(NTREE * HD + 255) / 256, 256, 0, stream>>>(Gx, Gh, bufA, NTREE);
        gemm2(bufA, nullptr, 0, 0, tW[1][0], tW[1][2], Gx,
              bufB, tW[1][1], tW[1][3], Gh, NTREE, 300, HD);
        gru_combine<<<(NTREE * HD + 255) / 256, 256, 0, stream>>>(Gx, Gh, bufB, NTREE);
    }

    // ---- 7. xt root rows <- xg_final[:128] (in-place in bufB) ----
    copy_block<<<(NB * HD + 255) / 256, 256, 0, stream>>>(xgfin, bufB, NB * HD);

    // ---- 8. tree GAT1 (8 heads x 100, K=100), out in-place in bufH ----
    gat(bufB, NTREE, HD, 8, 100, tc1W, tc1as, tc1ad, tc1b, tei, ET, bufG, bufH);
    // ---- 9. tree GAT2 (1 head x 100, K=800) -> xt_final at G+48MB ----
    gat(bufH, NTREE, 800, 1, 100, tc2W, tc2as, tc2ad, tc2b, tei, ET, bufG, xgfin);

    // ---- 10. scatter_mean over trees + classifier ----
    hipMemsetAsync(ssum, 0, (size_t)NB * HD * 4, stream);
    hipMemsetAsync(cnt, 0, (size_t)NB * 4, stream);
    scatter_mean_accum<<<(NTREE * HD + 255) / 256, 256, 0, stream>>>(xgfin, indices, ssum, cnt);
    fc_out<<<1, 512, 0, stream>>>(ssum, cnt, fcW, fcb, out);
}

// Round 2
// 5791.014 us; speedup vs baseline: 2.3570x; 2.3570x over previous
//
#include <hip/hip_runtime.h>

// ---------------------------------------------------------------------------
// Problem constants
// ---------------------------------------------------------------------------
#define NB    128
#define HD    100
#define NU    20000
#define NTG   10000
#define NTREE 30000
#define NG    30000
#define TT    20
#define EG    200000
#define ET    60000
#define VOC   50000

__device__ __forceinline__ float sigmoidf_(float x) {
    return __fdividef(1.f, 1.f + __expf(-x));
}
__device__ __forceinline__ float tanhf_(float x) {
    // 1 - 2/(e^{2x}+1): no NaN at +/-inf, ~1e-7 rel err
    return 1.f - __fdividef(2.f, __expf(2.f * x) + 1.f);
}

// ---------------------------------------------------------------------------
// Tiled GEMM: C[m][n] = sum_k A[m][k] * W[n][k]  (+bias) (+relu)
// 64x64 tile, K-chunk 20, up to 4 batched problem descriptors (blockIdx.z).
// ---------------------------------------------------------------------------
__global__ __launch_bounds__(256) void gemm_nt(
    const float* __restrict__ A0, const float* __restrict__ A1,
    const float* __restrict__ A2, const float* __restrict__ A3,
    const float* __restrict__ W0, const float* __restrict__ W1,
    const float* __restrict__ W2, const float* __restrict__ W3,
    float* __restrict__ C0, float* __restrict__ C1,
    float* __restrict__ C2, float* __restrict__ C3,
    const float* __restrict__ bias0, const float* __restrict__ bias1,
    int M0, int M1, int M2, int M3,
    int N, int K, int relu)
{
    const int z = blockIdx.z;
    const float* A; const float* W; float* C; const float* bias; int M;
    if      (z == 0) { A = A0; W = W0; C = C0; bias = bias0; M = M0; }
    else if (z == 1) { A = A1; W = W1; C = C1; bias = bias1; M = M1; }
    else if (z == 2) { A = A2; W = W2; C = C2; bias = nullptr; M = M2; }
    else             { A = A3; W = W3; C = C3; bias = nullptr; M = M3; }

    const int m0 = blockIdx.x * 64;
    if (m0 >= M) return;
    const int n0 = blockIdx.y * 64;

    __shared__ float As[20][68];
    __shared__ float Ws[20][68];

    const int tid = threadIdx.x;
    const int r0 = (tid >> 4) * 4;
    const int c0 = (tid & 15) * 4;

    // staging decomposition precomputed once (loop-invariant)
    int sr[5], sk[5];
#pragma unroll
    for (int it = 0; it < 5; ++it) {
        int idx = tid + it * 256;       // < 1280
        sr[it] = idx / 20;
        sk[it] = idx - sr[it] * 20;
    }

    float acc[4][4];
#pragma unroll
    for (int i = 0; i < 4; ++i)
#pragma unroll
        for (int j = 0; j < 4; ++j) acc[i][j] = 0.f;

    const int nch = (K + 19) / 20;
    for (int ch = 0; ch < nch; ++ch) {
        const int k0 = ch * 20;
#pragma unroll
        for (int it = 0; it < 5; ++it) {
            int m = m0 + sr[it], k = k0 + sk[it];
            float va = 0.f, vw = 0.f;
            if (k < K) {
                if (m < M)           va = A[(size_t)m * K + k];
                int n = n0 + sr[it];
                if (n < N)           vw = W[(size_t)n * K + k];
            }
            As[sk[it]][sr[it]] = va;
            Ws[sk[it]][sr[it]] = vw;
        }
        __syncthreads();
#pragma unroll
        for (int kk = 0; kk < 20; ++kk) {
            float4 a = *(const float4*)&As[kk][r0];
            float4 w = *(const float4*)&Ws[kk][c0];
            float av[4] = {a.x, a.y, a.z, a.w};
            float wv[4] = {w.x, w.y, w.z, w.w};
#pragma unroll
            for (int i = 0; i < 4; ++i)
#pragma unroll
                for (int j = 0; j < 4; ++j)
                    acc[i][j] = fmaf(av[i], wv[j], acc[i][j]);
        }
        __syncthreads();
    }

#pragma unroll
    for (int i = 0; i < 4; ++i) {
        int m = m0 + r0 + i;
        if (m >= M) continue;
        int n = n0 + c0;
        float v0 = acc[i][0], v1 = acc[i][1], v2 = acc[i][2], v3 = acc[i][3];
        if (bias) { v0 += bias[n]; v1 += bias[n+1]; v2 += bias[n+2]; v3 += bias[n+3]; }
        if (relu) { v0 = fmaxf(v0,0.f); v1 = fmaxf(v1,0.f); v2 = fmaxf(v2,0.f); v3 = fmaxf(v3,0.f); }
        if (n + 4 <= N) {
            float4 r4 = make_float4(v0, v1, v2, v3);
            *(float4*)&C[(size_t)m * N + n] = r4;
        } else {
            float vv[4] = {v0, v1, v2, v3};
            for (int j = 0; j < 4; ++j)
                if (n + j < N) C[(size_t)m * N + n + j] = vv[j];
        }
    }
}

// ---------------------------------------------------------------------------
// GRU combine. If nodes != nullptr, Gx comes from Etab[nodes[n*TT+t]] (fused
// layer-0 x-gate gather); else from dense Gx[n].
// ---------------------------------------------------------------------------
__global__ void gru_combine(
    const float* __restrict__ Etab, const int* __restrict__ nodes, int tstep,
    const float* __restrict__ Gx, const float* __restrict__ Gh,
    const float* __restrict__ bih, const float* __restrict__ bhh,
    float* __restrict__ h, int N)
{
    int t = blockIdx.x * blockDim.x + threadIdx.x;
    if (t >= N * HD) return;
    int n = t / HD, c = t - n * HD;
    const float* gx = nodes ? (Etab + (size_t)nodes[n * TT + tstep] * 300)
                            : (Gx + (size_t)n * 300);
    const float* gh = Gh + (size_t)n * 300;
    float xr = gx[c]        + bih[c];
    float xz = gx[HD + c]   + bih[HD + c];
    float xn = gx[2*HD + c] + bih[2*HD + c];
    float hr = gh[c]        + bhh[c];
    float hz = gh[HD + c]   + bhh[HD + c];
    float hn = gh[2*HD + c] + bhh[2*HD + c];
    float r  = sigmoidf_(xr + hr);
    float zz = sigmoidf_(xz + hz);
    float ng = tanhf_(xn + r * hn);
    h[t] = (1.f - zz) * ng + zz * h[t];
}

__global__ void build_xg(const float* __restrict__ hg, const float* __restrict__ ue,
                         float* __restrict__ xg)
{
    int tid = blockIdx.x * blockDim.x + threadIdx.x;
    if (tid >= NG * HD) return;
    int n = tid / HD, c = tid - n * HD;
    float v;
    if (n < NB)           v = hg[n * HD + c];
    else if (n < NB + NU) v = ue[(n - NB) * HD + c];
    else                  v = hg[(n - NU) * HD + c];
    xg[tid] = v;
}

__global__ void copy_block(const float* __restrict__ src, float* __restrict__ dst, int n)
{
    int t = blockIdx.x * blockDim.x + threadIdx.x;
    if (t < n) dst[t] = src[t];
}

// ---------------------------------------------------------------------------
// CSR build (per graph, reused by both GAT layers of the branch)
// ---------------------------------------------------------------------------
__global__ void csr_count(const int* __restrict__ ei, int E, int N, int* __restrict__ cnt)
{
    int e = blockIdx.x * blockDim.x + threadIdx.x;
    if (e >= E + N) return;
    int dst = (e < E) ? ei[E + e] : e - E;
    atomicAdd(&cnt[dst], 1);
}

__global__ void csr_scan(const int* __restrict__ cnt, int* __restrict__ off,
                         int* __restrict__ cur, int N)
{
    __shared__ int buf[256];
    __shared__ int carry;
    int tid = threadIdx.x;
    if (tid == 0) carry = 0;
    __syncthreads();
    for (int base = 0; base < N; base += 256) {
        int i = base + tid;
        int v = (i < N) ? cnt[i] : 0;
        buf[tid] = v;
        __syncthreads();
        for (int o = 1; o < 256; o <<= 1) {
            int t2 = (tid >= o) ? buf[tid - o] : 0;
            __syncthreads();
            buf[tid] += t2;
            __syncthreads();
        }
        int excl = buf[tid] - v + carry;
        if (i < N) { off[i] = excl; cur[i] = excl; }
        __syncthreads();
        if (tid == 0) carry += buf[255];
        __syncthreads();
    }
    if (tid == 0) off[N] = carry;
}

__global__ void csr_scatter(const int* __restrict__ ei, int E, int N,
                            int* __restrict__ cur, int* __restrict__ eidx)
{
    int e = blockIdx.x * blockDim.x + threadIdx.x;
    if (e >= E + N) return;
    int dst = (e < E) ? ei[E + e] : e - E;
    int pos = atomicAdd(&cur[dst], 1);
    eidx[pos] = e;
}

// ---------------------------------------------------------------------------
// GAT pieces
// ---------------------------------------------------------------------------
__global__ void gat_es_ed(const float* __restrict__ feat, const float* __restrict__ asrc,
                          const float* __restrict__ adst, float* __restrict__ es,
                          float* __restrict__ ed, int N, int heads, int C)
{
    int gid = blockIdx.x * blockDim.x + threadIdx.x;
    if (gid >= N * heads) return;
    int n = gid / heads, hd = gid - n * heads;
    const float4* hp  = (const float4*)(feat + ((size_t)n * heads + hd) * C);
    const float4* as4 = (const float4*)(asrc + (size_t)hd * C);
    const float4* ad4 = (const float4*)(adst + (size_t)hd * C);
    float s1 = 0.f, s2 = 0.f;
    for (int c = 0; c < C / 4; ++c) {
        float4 v = hp[c], a = as4[c], d = ad4[c];
        s1 += v.x*a.x + v.y*a.y + v.z*a.z + v.w*a.w;
        s2 += v.x*d.x + v.y*d.y + v.z*d.z + v.w*d.w;
    }
    es[gid] = s1; ed[gid] = s2;
}

__device__ __forceinline__ void atomic_max_f(float* addr, float v)
{
    if (v >= 0.f) atomicMax((int*)addr, __float_as_int(v));
    else          atomicMin((unsigned int*)addr, __float_as_uint(v));
}

__global__ void gat_edge_logit(const int* __restrict__ ei, int E, int N, int heads,
                               const float* __restrict__ es, const float* __restrict__ ed,
                               float* __restrict__ eb, float* __restrict__ m)
{
    int gid = blockIdx.x * blockDim.x + threadIdx.x;
    int EE = E + N;
    if (gid >= EE * heads) return;
    int idx = gid / heads, hd = gid - idx * heads;
    int src, dst;
    if (idx < E) { src = ei[idx]; dst = ei[E + idx]; } else { src = dst = idx - E; }
    float e = es[src * heads + hd] + ed[dst * heads + hd];
    e = e > 0.f ? e : 0.2f * e;
    eb[gid] = e;
    atomic_max_f(&m[dst * heads + hd], e);
}

__global__ void gat_edge_expsum(const int* __restrict__ ei, int E, int N, int heads,
                                float* __restrict__ eb, const float* __restrict__ m,
                                float* __restrict__ s)
{
    int gid = blockIdx.x * blockDim.x + threadIdx.x;
    int EE = E + N;
    if (gid >= EE * heads) return;
    int idx = gid / heads, hd = gid - idx * heads;
    int dst = (idx < E) ? ei[E + idx] : idx - E;
    float e = __expf(eb[gid] - m[dst * heads + hd]);
    eb[gid] = e;
    atomicAdd(&s[dst * heads + hd], e);
}

// per-(dst, chunk) wave gather; no atomics; bias+relu fused
template<int C, int VEC>
__global__ __launch_bounds__(256) void gat_accum_csr(
    const int* __restrict__ off, const int* __restrict__ eidx,
    const int* __restrict__ ei, int E,
    const float* __restrict__ eb, const float* __restrict__ s,
    const float* __restrict__ feat, const float* __restrict__ bias,
    float* __restrict__ outp, int N, int heads, int HC, int nchunk)
{
    int gt = blockIdx.x * blockDim.x + threadIdx.x;
    int w = gt >> 6, lane = gt & 63;
    int dst = w / nchunk, chunk = w - dst * nchunk;
    if (dst >= N) return;
    int c0 = chunk * 64 * VEC + lane * VEC;
    if (c0 >= HC) return;
    int hh[VEC]; float sinv[VEC], acc[VEC];
#pragma unroll
    for (int v = 0; v < VEC; ++v) {
        int c = c0 + v;
        hh[v] = c / C;
        sinv[v] = __fdividef(1.f, s[dst * heads + hh[v]]);
        acc[v] = 0.f;
    }
    int e0 = off[dst], e1 = off[dst + 1];
    for (int p = e0; p < e1; ++p) {
        int j = eidx[p];
        int src = (j < E) ? ei[j] : (j - E);
        const float* fr = feat + (size_t)src * HC + c0;
        float fv[VEC];
        if (VEC == 4) { float4 f = *(const float4*)fr; fv[0]=f.x; fv[1]=f.y; fv[2]=f.z; fv[3]=f.w; }
        else if (VEC == 2) { float2 f = *(const float2*)fr; fv[0]=f.x; fv[1]=f.y; }
        else fv[0] = fr[0];
#pragma unroll
        for (int v = 0; v < VEC; ++v)
            acc[v] += fv[v] * eb[(size_t)j * heads + hh[v]] * sinv[v];
    }
#pragma unroll
    for (int v = 0; v < VEC; ++v) {
        int c = c0 + v;
        outp[(size_t)dst * HC + c] = fmaxf(acc[v] + bias[c], 0.f);
    }
}

__global__ void scatter_mean_accum(const float* __restrict__ x, const int* __restrict__ idx,
                                   float* __restrict__ ssum, float* __restrict__ cnt)
{
    int t = blockIdx.x * blockDim.x + threadIdx.x;
    if (t >= NTREE * HD) return;
    int n = t / HD, c = t - n * HD;
    int b = idx[n];
    atomicAdd(&ssum[b * HD + c], x[t]);
    if (c == 0) atomicAdd(&cnt[b], 1.f);
}

__global__ void fc_out(const float* __restrict__ ssum, const float* __restrict__ cnt,
                       const float* __restrict__ W, const float* __restrict__ b,
                       float* __restrict__ out)
{
    int t = threadIdx.x;                 // 512 threads
    int bb = t >> 2, j = t & 3;
    float inv = __fdividef(1.f, fmaxf(cnt[bb], 1.f));
    float acc = b[j];
    for (int k = 0; k < HD; ++k) acc += ssum[bb * HD + k] * inv * W[j * HD + k];
    out[t] = acc;
}

// ---------------------------------------------------------------------------
// Host launcher
// ---------------------------------------------------------------------------
extern "C" void kernel_launch(void* const* d_in, const int* in_sizes, int n_in,
                              void* d_out, int out_size, void* d_ws, size_t ws_size,
                              hipStream_t stream)
{
    const float* user_feats = (const float*)d_in[1];
    const int*   gnf        = (const int*)d_in[2];
    const int*   gei        = (const int*)d_in[3];
    const int*   tnf        = (const int*)d_in[4];
    const int*   tei        = (const int*)d_in[5];
    const int*   indices    = (const int*)d_in[6];
    const float* h0g        = (const float*)d_in[7];
    const float* h0t        = (const float*)d_in[8];
    const float* temb       = (const float*)d_in[9];
    const float* gW[2][4] = {{(const float*)d_in[10], (const float*)d_in[11], (const float*)d_in[12], (const float*)d_in[13]},
                             {(const float*)d_in[14], (const float*)d_in[15], (const float*)d_in[16], (const float*)d_in[17]}};
    const float* tW[2][4] = {{(const float*)d_in[18], (const float*)d_in[19], (const float*)d_in[20], (const float*)d_in[21]},
                             {(const float*)d_in[22], (const float*)d_in[23], (const float*)d_in[24], (const float*)d_in[25]}};
    const float* uW1 = (const float*)d_in[26]; const float* ub1 = (const float*)d_in[27];
    const float* uW2 = (const float*)d_in[28]; const float* ub2 = (const float*)d_in[29];
    const float* gc1W = (const float*)d_in[30]; const float* gc1as = (const float*)d_in[31];
    const float* gc1ad = (const float*)d_in[32]; const float* gc1b = (const float*)d_in[33];
    const float* gc2W = (const float*)d_in[34]; const float* gc2as = (const float*)d_in[35];
    const float* gc2ad = (const float*)d_in[36]; const float* gc2b = (const float*)d_in[37];
    const float* tc1W = (const float*)d_in[38]; const float* tc1as = (const float*)d_in[39];
    const float* tc1ad = (const float*)d_in[40]; const float* tc1b = (const float*)d_in[41];
    const float* tc2W = (const float*)d_in[42]; const float* tc2as = (const float*)d_in[43];
    const float* tc2ad = (const float*)d_in[44]; const float* tc2b = (const float*)d_in[45];
    const float* fcW = (const float*)d_in[46]; const float* fcb = (const float*)d_in[47];
    float* out = (float*)d_out;

    // ---- workspace arena (decimal byte offsets; proven ws >= 227252736) ----
    char* ws = (char*)d_ws;
    const size_t NEED = 224200000;
    if (ws_size < NEED) return;

    float* R0    = (float*)(ws + 0);           // 96 MB region
    float* R1    = (float*)(ws + 96000000);    // 96 MB region
    float* H1    = (float*)(ws + 192000000);   // 12 MB (h1 / xt, in-place)
    float* XGF   = (float*)(ws + 204000000);   // 12 MB (xg, then xg_final)
    // tree GAT misc (outside R0/R1; alive while R0 is full)
    int*   TOFF  = (int*)(ws + 216000000);
    int*   TCUR  = (int*)(ws + 216200000);
    int*   TCNT  = (int*)(ws + 216400000);
    int*   TEIDX = (int*)(ws + 216600000);
    float* TES   = (float*)(ws + 217000000);
    float* TED   = (float*)(ws + 218000000);
    float* TM    = (float*)(ws + 219000000);
    float* TS    = (float*)(ws + 220000000);
    float* TEB   = (float*)(ws + 221000000);   // up to 2.88 MB
    float* SSUM  = (float*)(ws + 224000000);
    float* SCNT  = (float*)(ws + 224100000);

    // phase-GRU views
    float* ETAB = R0;                          // 60 MB
    float* G0   = (float*)(ws + 60000000);     // Gh0, up to 36 MB
    float* G1X  = R1;                          // up to 36 MB
    float* G1H  = (float*)(ws + 96000000 + 36000000);
    float* H0   = (float*)(ws + 96000000 + 72000000);  // 12 MB
    float* UE   = (float*)(ws + 96000000 + 84000000);  // 8 MB
    float* HID  = R0;                          // 8 MB scratch (pre-Etab)

    // graph GAT misc inside R0 tail (graph feat <= 61.44 MB)
    int*   GOFF  = (int*)(ws + 62000000);
    int*   GCUR  = (int*)(ws + 62200000);
    int*   GCNT  = (int*)(ws + 62400000);
    int*   GEIDX = (int*)(ws + 62600000);
    float* GES   = (float*)(ws + 64000000);
    float* GED   = (float*)(ws + 65000000);
    float* GM    = (float*)(ws + 66000000);
    float* GS    = (float*)(ws + 67000000);
    float* GEB   = (float*)(ws + 68000000);    // 7.36 MB
    // tree GAT2 small buffers
    float* FEAT2 = R0;                         // 12 MB
    float* XOUT2 = (float*)(ws + 30000000);    // 12 MB (tree GAT2 out)

    auto gemm1 = [&](const float* A, const float* W, const float* bias, float* C,
                     int M, int N, int K, int relu) {
        dim3 grid((M + 63) / 64, (N + 63) / 64, 1);
        gemm_nt<<<grid, 256, 0, stream>>>(A, nullptr, nullptr, nullptr,
                                          W, nullptr, nullptr, nullptr,
                                          C, nullptr, nullptr, nullptr,
                                          bias, nullptr, M, 0, 0, 0, N, K, relu);
    };
    auto gemm2 = [&](const float* A0, const float* W0, float* C0, int M0,
                     const float* A1, const float* W1, float* C1, int M1,
                     int N, int K) {
        int mx = M0 > M1 ? M0 : M1;
        dim3 grid((mx + 63) / 64, (N + 63) / 64, 2);
        gemm_nt<<<grid, 256, 0, stream>>>(A0, A1, nullptr, nullptr,
                                          W0, W1, nullptr, nullptr,
                                          C0, C1, nullptr, nullptr,
                                          nullptr, nullptr, M0, M1, 0, 0, N, K, 0);
    };

    auto csr_build = [&](const int* ei, int E, int N, int* cnt, int* off, int* cur, int* eidx) {
        hipMemsetAsync(cnt, 0, (size_t)N * 4, stream);
        csr_count<<<(E + N + 255) / 256, 256, 0, stream>>>(ei, E, N, cnt);
        csr_scan<<<1, 256, 0, stream>>>(cnt, off, cur, N);
        csr_scatter<<<(E + N + 255) / 256, 256, 0, stream>>>(ei, E, N, cur, eidx);
    };

    auto gat_pre = [&](const float* x, int N, int K, int heads, int C,
                       const float* W, const float* asrc, const float* adst,
                       const int* ei, int E, float* feat,
                       float* es, float* ed, float* m, float* s, float* ebuf) {
        int HC = heads * C;
        gemm1(x, W, nullptr, feat, N, HC, K, 0);
        gat_es_ed<<<(N * heads + 255) / 256, 256, 0, stream>>>(feat, asrc, adst, es, ed, N, heads, C);
        hipMemsetAsync(m, 0xFF, (size_t)N * heads * 4, stream);
        hipMemsetAsync(s, 0, (size_t)N * heads * 4, stream);
        int EE = E + N;
        gat_edge_logit<<<(EE * heads + 255) / 256, 256, 0, stream>>>(ei, E, N, heads, es, ed, ebuf, m);
        gat_edge_expsum<<<(EE * heads + 255) / 256, 256, 0, stream>>>(ei, E, N, heads, ebuf, m, s);
    };

    // ---- 1. user embed ----
    gemm1(user_feats, uW1, ub1, HID, NU, HD, 9, 1);
    gemm1(HID, uW2, ub2, UE, NU, HD, HD, 0);

    // ---- 2. graph branch: Etab + GRU ----
    gemm1(temb, gW[0][0], nullptr, ETAB, VOC, 300, HD, 0);   // Etab_g = temb @ gWih0^T
    hipMemcpyAsync(H0, h0g,            (size_t)NTG * HD * 4, hipMemcpyDeviceToDevice, stream);
    hipMemcpyAsync(H1, h0g + NTG * HD, (size_t)NTG * HD * 4, hipMemcpyDeviceToDevice, stream);
    for (int t = 0; t < TT; ++t) {
        gemm1(H0, gW[0][1], nullptr, G0, NTG, 300, HD, 0);                       // Gh0
        gru_combine<<<(NTG * HD + 255) / 256, 256, 0, stream>>>(
            ETAB, gnf, t, nullptr, G0, gW[0][2], gW[0][3], H0, NTG);
        gemm2(H0, gW[1][0], G1X, NTG, H1, gW[1][1], G1H, NTG, 300, HD);          // Gx1, Gh1
        gru_combine<<<(NTG * HD + 255) / 256, 256, 0, stream>>>(
            nullptr, nullptr, 0, G1X, G1H, gW[1][2], gW[1][3], H1, NTG);
    }

    // ---- 3. xg = concat(hg[:128], ue, hg[128:]) ----
    build_xg<<<(NG * HD + 255) / 256, 256, 0, stream>>>(H1, UE, XGF);

    // ---- 4. graph CSR + GAT1 (8x64) + GAT2 (1x100) ----
    csr_build(gei, EG, NG, GCNT, GOFF, GCUR, GEIDX);
    {   // GAT1: feat -> R0 (61.44 MB), out -> R1
        gat_pre(XGF, NG, HD, 8, 64, gc1W, gc1as, gc1ad, gei, EG, R0, GES, GED, GM, GS, GEB);
        int nchunk = 2;  // HC=512, VEC=4
        int waves = NG * nchunk;
        gat_accum_csr<64, 4><<<(waves + 3) / 4, 256, 0, stream>>>(
            GOFF, GEIDX, gei, EG, GEB, GS, R0, gc1b, R1, NG, 8, 512, nchunk);
    }
    {   // GAT2: feat -> FEAT2 (12 MB), out -> XGF (xg dead)
        gat_pre(R1, NG, 512, 1, 100, gc2W, gc2as, gc2ad, gei, EG, FEAT2, GES, GED, GM, GS, GEB);
        int nchunk = 1;  // HC=100, VEC=2
        int waves = NG * nchunk;
        gat_accum_csr<100, 2><<<(waves + 3) / 4, 256, 0, stream>>>(
            GOFF, GEIDX, gei, EG, GEB, GS, FEAT2, gc2b, XGF, NG, 1, 100, nchunk);
    }

    // ---- 5. tree branch: Etab + GRU ----
    gemm1(temb, tW[0][0], nullptr, ETAB, VOC, 300, HD, 0);   // Etab_t
    hipMemcpyAsync(H0, h0t,              (size_t)NTREE * HD * 4, hipMemcpyDeviceToDevice, stream);
    hipMemcpyAsync(H1, h0t + NTREE * HD, (size_t)NTREE * HD * 4, hipMemcpyDeviceToDevice, stream);
    for (int t = 0; t < TT; ++t) {
        gemm1(H0, tW[0][1], nullptr, G0, NTREE, 300, HD, 0);
        gru_combine<<<(NTREE * HD + 255) / 256, 256, 0, stream>>>(
            ETAB, tnf, t, nullptr, G0, tW[0][2], tW[0][3], H0, NTREE);
        gemm2(H0, tW[1][0], G1X, NTREE, H1, tW[1][1], G1H, NTREE, 300, HD);
        gru_combine<<<(NTREE * HD + 255) / 256, 256, 0, stream>>>(
            nullptr, nullptr, 0, G1X, G1H, tW[1][2], tW[1][3], H1, NTREE);
    }

    // ---- 6. xt roots <- xg_final[:128] (H1 is xt, in place) ----
    copy_block<<<(NB * HD + 255) / 256, 256, 0, stream>>>(XGF, H1, NB * HD);

    // ---- 7. tree CSR + GAT1 (8x100) + GAT2 (1x100) ----
    csr_build(tei, ET, NTREE, TCNT, TOFF, TCUR, TEIDX);
    {   // GAT1: feat -> R0 (96 MB full), out -> R1 (96 MB)
        gat_pre(H1, NTREE, HD, 8, 100, tc1W, tc1as, tc1ad, tei, ET, R0, TES, TED, TM, TS, TEB);
        int nchunk = 4;  // HC=800, VEC=4 (last chunk partial)
        int waves = NTREE * nchunk;
        gat_accum_csr<100, 4><<<(waves + 3) / 4, 256, 0, stream>>>(
            TOFF, TEIDX, tei, ET, TEB, TS, R0, tc1b, R1, NTREE, 8, 800, nchunk);
    }
    {   // GAT2: feat -> FEAT2, out -> XOUT2
        gat_pre(R1, NTREE, 800, 1, 100, tc2W, tc2as, tc2ad, tei, ET, FEAT2, TES, TED, TM, TS, TEB);
        int nchunk = 1;
        int waves = NTREE * nchunk;
        gat_accum_csr<100, 2><<<(waves + 3) / 4, 256, 0, stream>>>(
            TOFF, TEIDX, tei, ET, TEB, TS, FEAT2, tc2b, XOUT2, NTREE, 1, 100, nchunk);
    }

    // ---- 8. scatter_mean + classifier ----
    hipMemsetAsync(SSUM, 0, (size_t)NB * HD * 4, stream);
    hipMemsetAsync(SCNT, 0, (size_t)NB * 4, stream);
    scatter_mean_accum<<<(NTREE * HD + 255) / 256, 256, 0, stream>>>(XOUT2, indices, SSUM, SCNT);
    fc_out<<<1, 512, 0, stream>>>(SSUM, SCNT, fcW, fcb, out);
}

// Round 3
// 3393.483 us; speedup vs baseline: 4.0222x; 1.7065x over previous
//
#include <hip/hip_runtime.h>

// ---------------------------------------------------------------------------
// Problem constants
// ---------------------------------------------------------------------------
#define NB    128
#define HD    100
#define NU    20000
#define NTG   10000
#define NTREE 30000
#define NG    30000
#define TT    20
#define EG    200000
#define ET    60000
#define VOC   50000

typedef unsigned short u16;
typedef unsigned int   u32;
typedef __attribute__((ext_vector_type(8))) short short8;
typedef __attribute__((ext_vector_type(4))) float floatx4;

__device__ __forceinline__ float sigmoidf_(float x) {
    return __fdividef(1.f, 1.f + __expf(-x));
}
__device__ __forceinline__ float tanhf_(float x) {
    return 1.f - __fdividef(2.f, __expf(2.f * x) + 1.f);
}
__device__ __forceinline__ u16 f2bf(float f) {
    u32 u = __float_as_uint(f);
    u32 r = (u + 0x7fffu + ((u >> 16) & 1u)) >> 16;
    return (u16)r;
}
__device__ __forceinline__ float bf2f(u16 h) {
    return __uint_as_float(((u32)h) << 16);
}

// ---------------------------------------------------------------------------
// bf16 MFMA GEMM: C[m][n] = sum_k A[m][k]*W[n][k], fp32 accumulate.
// A: bf16 [M][lda] (lda mult of 32, zero-padded), W: bf16 [N][ldw].
// Out: fp32 (Cf) and/or bf16 (Cb), stride ldc. blockIdx.z batches 2 problems.
// Tile 64x64: 4 waves, each wave 16 rows x 64 cols (4 MFMA col-tiles).
// ---------------------------------------------------------------------------
#define LDST 40   // LDS row stride in bf16 elems (80 B): 2-way bank alias = free
__global__ __launch_bounds__(256) void gemm_mfma(
    const u16* __restrict__ A0, const u16* __restrict__ A1,
    const u16* __restrict__ B0, const u16* __restrict__ B1,
    float* __restrict__ Cf0, float* __restrict__ Cf1,
    u16* __restrict__ Cb0, u16* __restrict__ Cb1,
    int M0, int M1, int N, int Kt, int lda, int ldw, int ldc)
{
    const int z = blockIdx.z;
    const u16* __restrict__ A = z ? A1 : A0;
    const u16* __restrict__ B = z ? B1 : B0;
    float* __restrict__ Cf = z ? Cf1 : Cf0;
    u16*   __restrict__ Cb = z ? Cb1 : Cb0;
    const int M = z ? M1 : M0;

    const int m0 = blockIdx.x * 64;
    if (m0 >= M) return;
    const int n0 = blockIdx.y * 64;

    __shared__ u16 Als[64 * LDST];
    __shared__ u16 Wls[64 * LDST];

    const int tid  = threadIdx.x;
    const int wave = tid >> 6, lane = tid & 63;
    const int row  = tid >> 2, part = (tid & 3) * 8;   // staging: 64 rows x 4x8 k
    const int fr   = lane & 15, quad = lane >> 4;

    floatx4 acc[4];
#pragma unroll
    for (int t = 0; t < 4; ++t) acc[t] = (floatx4){0.f, 0.f, 0.f, 0.f};

    const int am = m0 + row;  const bool aok = am < M;
    const int wn = n0 + row;  const bool wok = wn < N;
    const uint4 z4 = {0u, 0u, 0u, 0u};

    for (int kk = 0; kk < Kt; ++kk) {
        uint4 av = aok ? *(const uint4*)(A + (size_t)am * lda + kk * 32 + part) : z4;
        uint4 wv = wok ? *(const uint4*)(B + (size_t)wn * ldw + kk * 32 + part) : z4;
        __syncthreads();   // previous chunk's frag reads done
        *(uint4*)&Als[row * LDST + part] = av;
        *(uint4*)&Wls[row * LDST + part] = wv;
        __syncthreads();
        short8 af = *(const short8*)&Als[((wave << 4) + fr) * LDST + quad * 8];
#pragma unroll
        for (int t = 0; t < 4; ++t) {
            short8 bf = *(const short8*)&Wls[((t << 4) + fr) * LDST + quad * 8];
            acc[t] = __builtin_amdgcn_mfma_f32_16x16x32_bf16(af, bf, acc[t], 0, 0, 0);
        }
    }

    const int orow0 = m0 + (wave << 4) + quad * 4;
#pragma unroll
    for (int t = 0; t < 4; ++t) {
        int col = n0 + (t << 4) + fr;
        if (col >= N) continue;
#pragma unroll
        for (int r = 0; r < 4; ++r) {
            int mr = orow0 + r;
            if (mr >= M) continue;
            float v = acc[t][r];
            if (Cf) Cf[(size_t)mr * ldc + col] = v;
            if (Cb) Cb[(size_t)mr * ldc + col] = f2bf(v);
        }
    }
}

// ---------------------------------------------------------------------------
// fp32 tiled GEMM (user-embed MLP only): C = A@W^T + b (+relu)
// ---------------------------------------------------------------------------
__global__ __launch_bounds__(256) void gemm_nt(
    const float* __restrict__ A, const float* __restrict__ W,
    const float* __restrict__ bias, float* __restrict__ C,
    int M, int N, int K, int relu)
{
    const int m0 = blockIdx.x * 64;
    const int n0 = blockIdx.y * 64;
    __shared__ float As[20][68];
    __shared__ float Ws[20][68];
    const int tid = threadIdx.x;
    const int r0 = (tid >> 4) * 4;
    const int c0 = (tid & 15) * 4;
    int sr[5], sk[5];
#pragma unroll
    for (int it = 0; it < 5; ++it) {
        int idx = tid + it * 256;
        sr[it] = idx / 20; sk[it] = idx - sr[it] * 20;
    }
    float acc[4][4];
#pragma unroll
    for (int i = 0; i < 4; ++i)
#pragma unroll
        for (int j = 0; j < 4; ++j) acc[i][j] = 0.f;
    const int nch = (K + 19) / 20;
    for (int ch = 0; ch < nch; ++ch) {
        const int k0 = ch * 20;
#pragma unroll
        for (int it = 0; it < 5; ++it) {
            int m = m0 + sr[it], k = k0 + sk[it];
            float va = 0.f, vw = 0.f;
            if (k < K) {
                if (m < M) va = A[(size_t)m * K + k];
                int n = n0 + sr[it];
                if (n < N) vw = W[(size_t)n * K + k];
            }
            As[sk[it]][sr[it]] = va;
            Ws[sk[it]][sr[it]] = vw;
        }
        __syncthreads();
#pragma unroll
        for (int kkk = 0; kkk < 20; ++kkk) {
            float4 a = *(const float4*)&As[kkk][r0];
            float4 w = *(const float4*)&Ws[kkk][c0];
            float av[4] = {a.x, a.y, a.z, a.w};
            float wv[4] = {w.x, w.y, w.z, w.w};
#pragma unroll
            for (int i = 0; i < 4; ++i)
#pragma unroll
                for (int j = 0; j < 4; ++j)
                    acc[i][j] = fmaf(av[i], wv[j], acc[i][j]);
        }
        __syncthreads();
    }
#pragma unroll
    for (int i = 0; i < 4; ++i) {
        int m = m0 + r0 + i;
        if (m >= M) continue;
#pragma unroll
        for (int j = 0; j < 4; ++j) {
            int n = n0 + c0 + j;
            if (n >= N) continue;
            float v = acc[i][j] + (bias ? bias[n] : 0.f);
            if (relu) v = fmaxf(v, 0.f);
            C[(size_t)m * N + n] = v;
        }
    }
}

// ---------------------------------------------------------------------------
// fp32 [M][K] -> bf16 [M][ldk], zero-padded cols K..ldk
// ---------------------------------------------------------------------------
__global__ void convert_pad(const float* __restrict__ src, u16* __restrict__ dst,
                            int M, int K, int ldk)
{
    int t = blockIdx.x * blockDim.x + threadIdx.x;
    if (t >= M * ldk) return;
    int n = t / ldk, c = t - n * ldk;
    dst[t] = (c < K) ? f2bf(src[(size_t)n * K + c]) : (u16)0;
}

// ---------------------------------------------------------------------------
// GRU combine (gates in bf16). Writes h fp32 [N][100] and bf16 [N][128].
// ---------------------------------------------------------------------------
__global__ void gru_combine(
    const u16* __restrict__ Etab, const int* __restrict__ nodes, int tstep,
    const u16* __restrict__ Gx, const u16* __restrict__ Gh,
    const float* __restrict__ bih, const float* __restrict__ bhh,
    float* __restrict__ hf, u16* __restrict__ hb, int N)
{
    int t = blockIdx.x * blockDim.x + threadIdx.x;
    if (t >= N * HD) return;
    int n = t / HD, c = t - n * HD;
    const u16* gx = nodes ? (Etab + (size_t)nodes[n * TT + tstep] * 300)
                          : (Gx + (size_t)n * 300);
    const u16* gh = Gh + (size_t)n * 300;
    float xr = bf2f(gx[c])        + bih[c];
    float xz = bf2f(gx[HD + c])   + bih[HD + c];
    float xn = bf2f(gx[2*HD + c]) + bih[2*HD + c];
    float hr = bf2f(gh[c])        + bhh[c];
    float hz = bf2f(gh[HD + c])   + bhh[HD + c];
    float hn = bf2f(gh[2*HD + c]) + bhh[2*HD + c];
    float r  = sigmoidf_(xr + hr);
    float zz = sigmoidf_(xz + hz);
    float ng = tanhf_(xn + r * hn);
    float hv = hf[t];
    float o  = (1.f - zz) * ng + zz * hv;
    hf[t] = o;
    hb[(size_t)n * 128 + c] = f2bf(o);
}

// xg (bf16, [NG][128] padded) = concat(hg[:128], ue, hg[128:])
__global__ void build_xg_bf(const float* __restrict__ hg, const float* __restrict__ ue,
                            u16* __restrict__ xgb)
{
    int t = blockIdx.x * blockDim.x + threadIdx.x;
    if (t >= NG * 128) return;
    int n = t / 128, c = t - n * 128;
    u16 o = 0;
    if (c < HD) {
        float v;
        if (n < NB)           v = hg[n * HD + c];
        else if (n < NB + NU) v = ue[(n - NB) * HD + c];
        else                  v = hg[(n - NU) * HD + c];
        o = f2bf(v);
    }
    xgb[t] = o;
}

// tree roots: H1b rows[0:128) <- xg_final fp32
__global__ void set_roots(const float* __restrict__ src, u16* __restrict__ hb)
{
    int t = blockIdx.x * blockDim.x + threadIdx.x;
    if (t >= NB * HD) return;
    int n = t / HD, c = t - n * HD;
    hb[(size_t)n * 128 + c] = f2bf(src[t]);
}

// ---------------------------------------------------------------------------
// CSR build
// ---------------------------------------------------------------------------
__global__ void csr_count(const int* __restrict__ ei, int E, int N, int* __restrict__ cnt)
{
    int e = blockIdx.x * blockDim.x + threadIdx.x;
    if (e >= E + N) return;
    int dst = (e < E) ? ei[E + e] : e - E;
    atomicAdd(&cnt[dst], 1);
}

__global__ void csr_scan(const int* __restrict__ cnt, int* __restrict__ off,
                         int* __restrict__ cur, int N)
{
    __shared__ int buf[256];
    __shared__ int carry;
    int tid = threadIdx.x;
    if (tid == 0) carry = 0;
    __syncthreads();
    for (int base = 0; base < N; base += 256) {
        int i = base + tid;
        int v = (i < N) ? cnt[i] : 0;
        buf[tid] = v;
        __syncthreads();
        for (int o = 1; o < 256; o <<= 1) {
            int t2 = (tid >= o) ? buf[tid - o] : 0;
            __syncthreads();
            buf[tid] += t2;
            __syncthreads();
        }
        int excl = buf[tid] - v + carry;
        if (i < N) { off[i] = excl; cur[i] = excl; }
        __syncthreads();
        if (tid == 0) carry += buf[255];
        __syncthreads();
    }
    if (tid == 0) off[N] = carry;
}

__global__ void csr_scatter(const int* __restrict__ ei, int E, int N,
                            int* __restrict__ cur, int* __restrict__ eidx)
{
    int e = blockIdx.x * blockDim.x + threadIdx.x;
    if (e >= E + N) return;
    int dst = (e < E) ? ei[E + e] : e - E;
    int pos = atomicAdd(&cur[dst], 1);
    eidx[pos] = e;
}

// ---------------------------------------------------------------------------
// GAT pieces
// ---------------------------------------------------------------------------
__global__ void gat_es_ed(const float* __restrict__ feat, const float* __restrict__ asrc,
                          const float* __restrict__ adst, float* __restrict__ es,
                          float* __restrict__ ed, int N, int heads, int C)
{
    int gid = blockIdx.x * blockDim.x + threadIdx.x;
    if (gid >= N * heads) return;
    int n = gid / heads, hd = gid - n * heads;
    const float4* hp  = (const float4*)(feat + ((size_t)n * heads + hd) * C);
    const float4* as4 = (const float4*)(asrc + (size_t)hd * C);
    const float4* ad4 = (const float4*)(adst + (size_t)hd * C);
    float s1 = 0.f, s2 = 0.f;
    for (int c = 0; c < C / 4; ++c) {
        float4 v = hp[c], a = as4[c], d = ad4[c];
        s1 += v.x*a.x + v.y*a.y + v.z*a.z + v.w*a.w;
        s2 += v.x*d.x + v.y*d.y + v.z*d.z + v.w*d.w;
    }
    es[gid] = s1; ed[gid] = s2;
}

__device__ __forceinline__ void atomic_max_f(float* addr, float v)
{
    if (v >= 0.f) atomicMax((int*)addr, __float_as_int(v));
    else          atomicMin((unsigned int*)addr, __float_as_uint(v));
}

__global__ void gat_edge_logit(const int* __restrict__ ei, int E, int N, int heads,
                               const float* __restrict__ es, const float* __restrict__ ed,
                               float* __restrict__ eb, float* __restrict__ m)
{
    int gid = blockIdx.x * blockDim.x + threadIdx.x;
    int EE = E + N;
    if (gid >= EE * heads) return;
    int idx = gid / heads, hd = gid - idx * heads;
    int src, dst;
    if (idx < E) { src = ei[idx]; dst = ei[E + idx]; } else { src = dst = idx - E; }
    float e = es[src * heads + hd] + ed[dst * heads + hd];
    e = e > 0.f ? e : 0.2f * e;
    eb[gid] = e;
    atomic_max_f(&m[dst * heads + hd], e);
}

__global__ void gat_edge_expsum(const int* __restrict__ ei, int E, int N, int heads,
                                float* __restrict__ eb, const float* __restrict__ m,
                                float* __restrict__ s)
{
    int gid = blockIdx.x * blockDim.x + threadIdx.x;
    int EE = E + N;
    if (gid >= EE * heads) return;
    int idx = gid / heads, hd = gid - idx * heads;
    int dst = (idx < E) ? ei[E + idx] : idx - E;
    float e = __expf(eb[gid] - m[dst * heads + hd]);
    eb[gid] = e;
    atomicAdd(&s[dst * heads + hd], e);
}

// per-(dst, chunk) wave gather; no atomics; bias+relu fused; dual dtype out
template<int C, int VEC>
__global__ __launch_bounds__(256) void gat_accum_csr(
    const int* __restrict__ off, const int* __restrict__ eidx,
    const int* __restrict__ ei, int E,
    const float* __restrict__ eb, const float* __restrict__ s,
    const float* __restrict__ feat, const float* __restrict__ bias,
    float* __restrict__ outf, u16* __restrict__ outb,
    int N, int heads, int HC, int nchunk)
{
    int gt = blockIdx.x * blockDim.x + threadIdx.x;
    int w = gt >> 6, lane = gt & 63;
    int dst = w / nchunk, chunk = w - dst * nchunk;
    if (dst >= N) return;
    int c0 = chunk * 64 * VEC + lane * VEC;
    if (c0 >= HC) return;
    int hh[VEC]; float sinv[VEC], acc[VEC];
#pragma unroll
    for (int v = 0; v < VEC; ++v) {
        int c = c0 + v;
        hh[v] = c / C;
        sinv[v] = __fdividef(1.f, s[dst * heads + hh[v]]);
        acc[v] = 0.f;
    }
    int e0 = off[dst], e1 = off[dst + 1];
    for (int p = e0; p < e1; ++p) {
        int j = eidx[p];
        int src = (j < E) ? ei[j] : (j - E);
        const float* fr = feat + (size_t)src * HC + c0;
        float fv[VEC];
        if (VEC == 4) { float4 f = *(const float4*)fr; fv[0]=f.x; fv[1]=f.y; fv[2]=f.z; fv[3]=f.w; }
        else if (VEC == 2) { float2 f = *(const float2*)fr; fv[0]=f.x; fv[1]=f.y; }
        else fv[0] = fr[0];
#pragma unroll
        for (int v = 0; v < VEC; ++v)
            acc[v] += fv[v] * eb[(size_t)j * heads + hh[v]] * sinv[v];
    }
#pragma unroll
    for (int v = 0; v < VEC; ++v) {
        int c = c0 + v;
        float o = fmaxf(acc[v] + bias[c], 0.f);
        if (outf) outf[(size_t)dst * HC + c] = o;
        if (outb) outb[(size_t)dst * HC + c] = f2bf(o);
    }
}

__global__ void scatter_mean_accum(const float* __restrict__ x, const int* __restrict__ idx,
                                   float* __restrict__ ssum, float* __restrict__ cnt)
{
    int t = blockIdx.x * blockDim.x + threadIdx.x;
    if (t >= NTREE * HD) return;
    int n = t / HD, c = t - n * HD;
    int b = idx[n];
    atomicAdd(&ssum[b * HD + c], x[t]);
    if (c == 0) atomicAdd(&cnt[b], 1.f);
}

__global__ void fc_out(const float* __restrict__ ssum, const float* __restrict__ cnt,
                       const float* __restrict__ W, const float* __restrict__ b,
                       float* __restrict__ out)
{
    int t = threadIdx.x;                 // 512 threads
    int bb = t >> 2, j = t & 3;
    float inv = __fdividef(1.f, fmaxf(cnt[bb], 1.f));
    float acc = b[j];
    for (int k = 0; k < HD; ++k) acc += ssum[bb * HD + k] * inv * W[j * HD + k];
    out[t] = acc;
}

// ---------------------------------------------------------------------------
// Host launcher
// ---------------------------------------------------------------------------
extern "C" void kernel_launch(void* const* d_in, const int* in_sizes, int n_in,
                              void* d_out, int out_size, void* d_ws, size_t ws_size,
                              hipStream_t stream)
{
    const float* user_feats = (const float*)d_in[1];
    const int*   gnf        = (const int*)d_in[2];
    const int*   gei        = (const int*)d_in[3];
    const int*   tnf        = (const int*)d_in[4];
    const int*   tei        = (const int*)d_in[5];
    const int*   indices    = (const int*)d_in[6];
    const float* h0g        = (const float*)d_in[7];
    const float* h0t        = (const float*)d_in[8];
    const float* temb       = (const float*)d_in[9];
    const float* gW[2][4] = {{(const float*)d_in[10], (const float*)d_in[11], (const float*)d_in[12], (const float*)d_in[13]},
                             {(const float*)d_in[14], (const float*)d_in[15], (const float*)d_in[16], (const float*)d_in[17]}};
    const float* tW[2][4] = {{(const float*)d_in[18], (const float*)d_in[19], (const float*)d_in[20], (const float*)d_in[21]},
                             {(const float*)d_in[22], (const float*)d_in[23], (const float*)d_in[24], (const float*)d_in[25]}};
    const float* uW1 = (const float*)d_in[26]; const float* ub1 = (const float*)d_in[27];
    const float* uW2 = (const float*)d_in[28]; const float* ub2 = (const float*)d_in[29];
    const float* gc1W = (const float*)d_in[30]; const float* gc1as = (const float*)d_in[31];
    const float* gc1ad = (const float*)d_in[32]; const float* gc1b = (const float*)d_in[33];
    const float* gc2W = (const float*)d_in[34]; const float* gc2as = (const float*)d_in[35];
    const float* gc2ad = (const float*)d_in[36]; const float* gc2b = (const float*)d_in[37];
    const float* tc1W = (const float*)d_in[38]; const float* tc1as = (const float*)d_in[39];
    const float* tc1ad = (const float*)d_in[40]; const float* tc1b = (const float*)d_in[41];
    const float* tc2W = (const float*)d_in[42]; const float* tc2as = (const float*)d_in[43];
    const float* tc2ad = (const float*)d_in[44]; const float* tc2b = (const float*)d_in[45];
    const float* fcW = (const float*)d_in[46]; const float* fcb = (const float*)d_in[47];
    float* out = (float*)d_out;

    char* ws = (char*)d_ws;
    const size_t NEED = 226100000;
    if (ws_size < NEED) return;

    // ---- persistent / phase buffers (byte offsets, all 16B-aligned) ----
    float* XGF    = (float*)(ws + 0);            // 12 MB  xg_final fp32 [NG][100]
    u16*   TEMB_B = (u16*)(ws + 12000000);       // 12.8 MB [VOC][128]
    u16*   ETAB_B = (u16*)(ws + 24800000);       // 30 MB  [VOC][300]
    float* H0F    = (float*)(ws + 54800000);     // 12 MB
    u16*   H0B    = (u16*)(ws + 66800000);       // 7.68 MB [M][128]
    float* H1F    = (float*)(ws + 74500000);     // 12 MB
    u16*   GH0_B  = (u16*)(ws + 94200000);       // 18 MB [M][300]
    u16*   G1X_B  = (u16*)(ws + 112200000);      // 18 MB
    u16*   G1H_B  = (u16*)(ws + 130200000);      // 18 MB
    float* UE     = (float*)(ws + 148200000);    // 8 MB
    float* HID    = (float*)(ws + 156200000);    // 8 MB
    u16*   H1B    = (u16*)(ws + 204000000);      // 7.68 MB [30000][128]
    u16*   WARENA = (u16*)(ws + 212000000);      // 1 MB
    int*   COFF   = (int*)(ws + 213000000);
    int*   CCUR   = (int*)(ws + 213200000);
    int*   CCNT   = (int*)(ws + 213400000);
    int*   CEIDX  = (int*)(ws + 213600000);      // 1 MB
    float* ESB    = (float*)(ws + 214600000);
    float* EDB    = (float*)(ws + 215600000);
    float* MB     = (float*)(ws + 216600000);
    float* SB     = (float*)(ws + 217600000);
    float* EBB    = (float*)(ws + 218600000);    // 7.36 MB
    float* SSUM   = (float*)(ws + 226000000);
    float* SCNT   = (float*)(ws + 226060000);

    // graph-GAT overlays (GRU gate/Etab regions dead)
    u16*   XG_B   = (u16*)(ws + 24800000);       // 7.68 MB
    float* GFEAT1 = (float*)(ws + 32500000);     // 61.44 MB fp32 [NG][512]
    u16*   GOUT1B = (u16*)(ws + 94200000);       // 30.72 MB [NG][512]
    float* GFEAT2 = (float*)(ws + 124920000);    // 12 MB
    // tree-GAT overlays
    float* TFEAT1 = (float*)(ws + 0);            // 96 MB fp32 [NTREE][800]
    u16*   TOUT1B = (u16*)(ws + 96000000);       // 48 MB [NTREE][800]
    float* TFEAT2 = (float*)(ws + 144000000);    // 12 MB
    float* XOUT2  = (float*)(ws + 156000000);    // 12 MB

    // weight arena slots (u16 elem offsets)
    u16* W_IH0 = WARENA + 0;        // [300][128]
    u16* W_HH0 = WARENA + 38400;
    u16* W_IH1 = WARENA + 76800;
    u16* W_HH1 = WARENA + 115200;
    u16* W_G1  = WARENA + 153600;   // gc1W [512][128] / tc1W [800][128]
    u16* W_G2  = WARENA + 256000;   // gc2W [100][512] / tc2W [100][800]

    auto cvt = [&](const float* src, u16* dst, int M, int K, int ldk) {
        convert_pad<<<((size_t)M * ldk + 255) / 256, 256, 0, stream>>>(src, dst, M, K, ldk);
    };
    auto mfma1 = [&](const u16* A, int lda, const u16* W, int ldw,
                     float* Cf, u16* Cb, int ldc, int M, int N, int Kt) {
        dim3 grid((M + 63) / 64, (N + 63) / 64, 1);
        gemm_mfma<<<grid, 256, 0, stream>>>(A, nullptr, W, nullptr,
                                            Cf, nullptr, Cb, nullptr,
                                            M, 0, N, Kt, lda, ldw, ldc);
    };
    auto mfma2b = [&](const u16* A0, const u16* W0, u16* C0,
                      const u16* A1, const u16* W1, u16* C1,
                      int M, int N, int Kt, int lda, int ldw, int ldc) {
        dim3 grid((M + 63) / 64, (N + 63) / 64, 2);
        gemm_mfma<<<grid, 256, 0, stream>>>(A0, A1, W0, W1,
                                            nullptr, nullptr, C0, C1,
                                            M, M, N, Kt, lda, ldw, ldc);
    };
    auto csr_build = [&](const int* ei, int E, int N) {
        hipMemsetAsync(CCNT, 0, (size_t)N * 4, stream);
        csr_count<<<(E + N + 255) / 256, 256, 0, stream>>>(ei, E, N, CCNT);
        csr_scan<<<1, 256, 0, stream>>>(CCNT, COFF, CCUR, N);
        csr_scatter<<<(E + N + 255) / 256, 256, 0, stream>>>(ei, E, N, CCUR, CEIDX);
    };
    auto gat_pre = [&](const float* feat, int N, int heads, int C,
                       const float* asrc, const float* adst, const int* ei, int E) {
        gat_es_ed<<<(N * heads + 255) / 256, 256, 0, stream>>>(feat, asrc, adst, ESB, EDB, N, heads, C);
        hipMemsetAsync(MB, 0xFF, (size_t)N * heads * 4, stream);
        hipMemsetAsync(SB, 0, (size_t)N * heads * 4, stream);
        int EE = E + N;
        gat_edge_logit<<<(EE * heads + 255) / 256, 256, 0, stream>>>(ei, E, N, heads, ESB, EDB, EBB, MB);
        gat_edge_expsum<<<(EE * heads + 255) / 256, 256, 0, stream>>>(ei, E, N, heads, EBB, MB, SB);
    };

    // ================= 1. user embed (fp32) =================
    {
        dim3 g1((NU + 63) / 64, (HD + 63) / 64, 1);
        gemm_nt<<<g1, 256, 0, stream>>>(user_feats, uW1, ub1, HID, NU, HD, 9, 1);
        gemm_nt<<<g1, 256, 0, stream>>>(HID, uW2, ub2, UE, NU, HD, HD, 0);
    }

    // ================= 2. shared converts =================
    cvt(temb, TEMB_B, VOC, HD, 128);

    // ================= 3. graph branch =================
    cvt(gW[0][0], W_IH0, 300, HD, 128);
    cvt(gW[0][1], W_HH0, 300, HD, 128);
    cvt(gW[1][0], W_IH1, 300, HD, 128);
    cvt(gW[1][1], W_HH1, 300, HD, 128);
    mfma1(TEMB_B, 128, W_IH0, 128, nullptr, ETAB_B, 300, VOC, 300, 4);   // Etab_g

    hipMemcpyAsync(H0F, h0g,            (size_t)NTG * HD * 4, hipMemcpyDeviceToDevice, stream);
    hipMemcpyAsync(H1F, h0g + NTG * HD, (size_t)NTG * HD * 4, hipMemcpyDeviceToDevice, stream);
    cvt(h0g,            H0B, NTG, HD, 128);
    cvt(h0g + NTG * HD, H1B, NTG, HD, 128);

    for (int t = 0; t < TT; ++t) {
        mfma1(H0B, 128, W_HH0, 128, nullptr, GH0_B, 300, NTG, 300, 4);
        gru_combine<<<(NTG * HD + 255) / 256, 256, 0, stream>>>(
            ETAB_B, gnf, t, nullptr, GH0_B, gW[0][2], gW[0][3], H0F, H0B, NTG);
        mfma2b(H0B, W_IH1, G1X_B, H1B, W_HH1, G1H_B, NTG, 300, 4, 128, 128, 300);
        gru_combine<<<(NTG * HD + 255) / 256, 256, 0, stream>>>(
            nullptr, nullptr, 0, G1X_B, G1H_B, gW[1][2], gW[1][3], H1F, H1B, NTG);
    }

    build_xg_bf<<<(NG * 128 + 255) / 256, 256, 0, stream>>>(H1F, UE, XG_B);

    csr_build(gei, EG, NG);
    cvt(gc1W, W_G1, 512, HD, 128);
    cvt(gc2W, W_G2, 100, 512, 512);
    {   // graph GAT1: 8 heads x 64
        mfma1(XG_B, 128, W_G1, 128, GFEAT1, nullptr, 512, NG, 512, 4);
        gat_pre(GFEAT1, NG, 8, 64, gc1as, gc1ad, gei, EG);
        int waves = NG * 2;   // HC=512, VEC=4, nchunk=2
        gat_accum_csr<64, 4><<<(waves + 3) / 4, 256, 0, stream>>>(
            COFF, CEIDX, gei, EG, EBB, SB, GFEAT1, gc1b, nullptr, GOUT1B, NG, 8, 512, 2);
    }
    {   // graph GAT2: 1 head x 100
        mfma1(GOUT1B, 512, W_G2, 512, GFEAT2, nullptr, 100, NG, 100, 16);
        gat_pre(GFEAT2, NG, 1, 100, gc2as, gc2ad, gei, EG);
        int waves = NG;       // HC=100, VEC=2, nchunk=1
        gat_accum_csr<100, 2><<<(waves + 3) / 4, 256, 0, stream>>>(
            COFF, CEIDX, gei, EG, EBB, SB, GFEAT2, gc2b, XGF, nullptr, NG, 1, 100, 1);
    }

    // ================= 4. tree branch =================
    cvt(tW[0][0], W_IH0, 300, HD, 128);
    cvt(tW[0][1], W_HH0, 300, HD, 128);
    cvt(tW[1][0], W_IH1, 300, HD, 128);
    cvt(tW[1][1], W_HH1, 300, HD, 128);
    mfma1(TEMB_B, 128, W_IH0, 128, nullptr, ETAB_B, 300, VOC, 300, 4);   // Etab_t

    hipMemcpyAsync(H0F, h0t,              (size_t)NTREE * HD * 4, hipMemcpyDeviceToDevice, stream);
    hipMemcpyAsync(H1F, h0t + NTREE * HD, (size_t)NTREE * HD * 4, hipMemcpyDeviceToDevice, stream);
    cvt(h0t,              H0B, NTREE, HD, 128);
    cvt(h0t + NTREE * HD, H1B, NTREE, HD, 128);

    for (int t = 0; t < TT; ++t) {
        mfma1(H0B, 128, W_HH0, 128, nullptr, GH0_B, 300, NTREE, 300, 4);
        gru_combine<<<(NTREE * HD + 255) / 256, 256, 0, stream>>>(
            ETAB_B, tnf, t, nullptr, GH0_B, tW[0][2], tW[0][3], H0F, H0B, NTREE);
        mfma2b(H0B, W_IH1, G1X_B, H1B, W_HH1, G1H_B, NTREE, 300, 4, 128, 128, 300);
        gru_combine<<<(NTREE * HD + 255) / 256, 256, 0, stream>>>(
            nullptr, nullptr, 0, G1X_B, G1H_B, tW[1][2], tW[1][3], H1F, H1B, NTREE);
    }

    set_roots<<<(NB * HD + 255) / 256, 256, 0, stream>>>(XGF, H1B);

    csr_build(tei, ET, NTREE);
    cvt(tc1W, W_G1, 800, HD, 128);
    cvt(tc2W, W_G2, 100, 800, 800);
    {   // tree GAT1: 8 heads x 100
        mfma1(H1B, 128, W_G1, 128, TFEAT1, nullptr, 800, NTREE, 800, 4);
        gat_pre(TFEAT1, NTREE, 8, 100, tc1as, tc1ad, tei, ET);
        int waves = NTREE * 4;  // HC=800, VEC=4, nchunk=4
        gat_accum_csr<100, 4><<<(waves + 3) / 4, 256, 0, stream>>>(
            COFF, CEIDX, tei, ET, EBB, SB, TFEAT1, tc1b, nullptr, TOUT1B, NTREE, 8, 800, 4);
    }
    {   // tree GAT2: 1 head x 100
        mfma1(TOUT1B, 800, W_G2, 800, TFEAT2, nullptr, 100, NTREE, 100, 25);
        gat_pre(TFEAT2, NTREE, 1, 100, tc2as, tc2ad, tei, ET);
        int waves = NTREE;
        gat_accum_csr<100, 2><<<(waves + 3) / 4, 256, 0, stream>>>(
            COFF, CEIDX, tei, ET, EBB, SB, TFEAT2, tc2b, XOUT2, nullptr, NTREE, 1, 100, 1);
    }

    // ================= 5. scatter_mean + classifier =================
    hipMemsetAsync(SSUM, 0, (size_t)NB * HD * 4, stream);
    hipMemsetAsync(SCNT, 0, (size_t)NB * 4, stream);
    scatter_mean_accum<<<(NTREE * HD + 255) / 256, 256, 0, stream>>>(XOUT2, indices, SSUM, SCNT);
    fc_out<<<1, 512, 0, stream>>>(SSUM, SCNT, fcW, fcb, out);
}

// Round 4
// 3092.426 us; speedup vs baseline: 4.4138x; 1.0974x over previous
//
#include <hip/hip_runtime.h>

// ---------------------------------------------------------------------------
// Problem constants
// ---------------------------------------------------------------------------
#define NB    128
#define HD    100
#define NU    20000
#define NTG   10000
#define NTREE 30000
#define NG    30000
#define TT    20
#define EG    200000
#define ET    60000
#define VOC   50000

typedef unsigned short u16;
typedef unsigned int   u32;
typedef __attribute__((ext_vector_type(8))) short short8;
typedef __attribute__((ext_vector_type(4))) float floatx4;

__device__ __forceinline__ float sigmoidf_(float x) {
    return __fdividef(1.f, 1.f + __expf(-x));
}
__device__ __forceinline__ float tanhf_(float x) {
    return 1.f - __fdividef(2.f, __expf(2.f * x) + 1.f);
}
__device__ __forceinline__ u16 f2bf(float f) {
    u32 u = __float_as_uint(f);
    u32 r = (u + 0x7fffu + ((u >> 16) & 1u)) >> 16;
    return (u16)r;
}
__device__ __forceinline__ float bf2f(u16 h) {
    return __uint_as_float(((u32)h) << 16);
}

// ---------------------------------------------------------------------------
// Fused 2-layer GRU over all TT steps. Block owns 64 rows; h in LDS; the
// three weight matrices (Whh0, Wih1, Whh1) live in registers as persistent
// MFMA B-fragments (240 VGPRs). Layer-0 x-gates come from Etab gather.
// Weights are bf16 [320][128], zero-padded rows/cols.
// ---------------------------------------------------------------------------
#define NSLOT 5   // col tiles per wave: ct = wave + 4*s, 19 real tiles (304 cols)

__global__ __launch_bounds__(256, 1) void gru_fused(
    const u16* __restrict__ Etab,      // [VOC][300] bf16
    const int* __restrict__ nodes,     // [M][TT]
    const float* __restrict__ h0,      // [2][M][100] fp32
    const u16* __restrict__ Whh0,      // [320][128] bf16 padded
    const u16* __restrict__ Wih1,
    const u16* __restrict__ Whh1,
    const float* __restrict__ bih0, const float* __restrict__ bhh0,
    const float* __restrict__ bih1, const float* __restrict__ bhh1,
    u16* __restrict__ hout,            // [M][128] bf16 (cols 100..127 zero)
    int M)
{
    __shared__ float h0f[64 * 100];
    __shared__ float h1f[64 * 100];
    __shared__ u16   h0b[64 * 136];    // stride 136: rotates banks, 2-way max
    __shared__ u16   h1b[64 * 136];
    __shared__ u16   GA[64 * 300];
    __shared__ u16   GB[64 * 300];
    __shared__ int   nid[64];

    const int tid  = threadIdx.x;
    const int wave = tid >> 6, lane = tid & 63;
    const int fr   = lane & 15, quad = lane >> 4;
    const int m0   = blockIdx.x * 64;

    // persistent weight B-fragments
    short8 Bh0[NSLOT][4], Bx1[NSLOT][4], Bh1[NSLOT][4];
#pragma unroll
    for (int s = 0; s < NSLOT; ++s) {
        const int rowb = ((wave + 4 * s) * 16 + fr) * 128 + quad * 8;
#pragma unroll
        for (int kk = 0; kk < 4; ++kk) {
            Bh0[s][kk] = *(const short8*)(Whh0 + rowb + kk * 32);
            Bx1[s][kk] = *(const short8*)(Wih1 + rowb + kk * 32);
            Bh1[s][kk] = *(const short8*)(Whh1 + rowb + kk * 32);
        }
    }

    // init h state
    for (int i = tid; i < 64 * 136; i += 256) { h0b[i] = 0; h1b[i] = 0; }
    __syncthreads();
    for (int i = tid; i < 6400; i += 256) {
        int row = i / 100, c = i - row * 100;
        int gm = m0 + row;
        float v0 = 0.f, v1 = 0.f;
        if (gm < M) {
            v0 = h0[(size_t)gm * 100 + c];
            v1 = h0[(size_t)(M + gm) * 100 + c];
        }
        h0f[i] = v0; h1f[i] = v1;
        h0b[row * 136 + c] = f2bf(v0);
        h1b[row * 136 + c] = f2bf(v1);
    }
    __syncthreads();

    for (int t = 0; t < TT; ++t) {
        if (tid < 64) {
            int gm = m0 + tid;
            nid[tid] = (gm < M) ? nodes[(size_t)gm * TT + t] : 0;
        }
        // ---- Gh0 = h0b @ Whh0^T -> GA ----
#pragma unroll
        for (int rt = 0; rt < 4; ++rt) {
            short8 a[4];
#pragma unroll
            for (int kk = 0; kk < 4; ++kk)
                a[kk] = *(const short8*)&h0b[(rt * 16 + fr) * 136 + kk * 32 + quad * 8];
#pragma unroll
            for (int s = 0; s < NSLOT; ++s) {
                floatx4 acc = {0.f, 0.f, 0.f, 0.f};
#pragma unroll
                for (int kk = 0; kk < 4; ++kk)
                    acc = __builtin_amdgcn_mfma_f32_16x16x32_bf16(a[kk], Bh0[s][kk], acc, 0, 0, 0);
                int col = (wave + 4 * s) * 16 + fr;
                if (col < 300) {
                    int rbase = rt * 16 + quad * 4;
#pragma unroll
                    for (int r = 0; r < 4; ++r)
                        GA[(rbase + r) * 300 + col] = f2bf(acc[r]);
                }
            }
        }
        __syncthreads();
        // ---- combine layer 0 ----
        for (int i = tid; i < 6400; i += 256) {
            int row = i / 100, c = i - row * 100;
            const u16* ex = Etab + (size_t)nid[row] * 300;
            float xr = bf2f(ex[c])              + bih0[c];
            float xz = bf2f(ex[100 + c])        + bih0[100 + c];
            float xn = bf2f(ex[200 + c])        + bih0[200 + c];
            float hr = bf2f(GA[row * 300 + c])        + bhh0[c];
            float hz = bf2f(GA[row * 300 + 100 + c])  + bhh0[100 + c];
            float hn = bf2f(GA[row * 300 + 200 + c])  + bhh0[200 + c];
            float r  = sigmoidf_(xr + hr);
            float zz = sigmoidf_(xz + hz);
            float ng = tanhf_(xn + r * hn);
            float o  = (1.f - zz) * ng + zz * h0f[i];
            h0f[i] = o;
            h0b[row * 136 + c] = f2bf(o);
        }
        __syncthreads();
        // ---- Gx1 = h0b@Wih1^T -> GA ; Gh1 = h1b@Whh1^T -> GB ----
#pragma unroll
        for (int rt = 0; rt < 4; ++rt) {
            short8 a0[4], a1[4];
#pragma unroll
            for (int kk = 0; kk < 4; ++kk) {
                a0[kk] = *(const short8*)&h0b[(rt * 16 + fr) * 136 + kk * 32 + quad * 8];
                a1[kk] = *(const short8*)&h1b[(rt * 16 + fr) * 136 + kk * 32 + quad * 8];
            }
#pragma unroll
            for (int s = 0; s < NSLOT; ++s) {
                floatx4 ax = {0.f, 0.f, 0.f, 0.f};
                floatx4 ah = {0.f, 0.f, 0.f, 0.f};
#pragma unroll
                for (int kk = 0; kk < 4; ++kk) {
                    ax = __builtin_amdgcn_mfma_f32_16x16x32_bf16(a0[kk], Bx1[s][kk], ax, 0, 0, 0);
                    ah = __builtin_amdgcn_mfma_f32_16x16x32_bf16(a1[kk], Bh1[s][kk], ah, 0, 0, 0);
                }
                int col = (wave + 4 * s) * 16 + fr;
                if (col < 300) {
                    int rbase = rt * 16 + quad * 4;
#pragma unroll
                    for (int r = 0; r < 4; ++r) {
                        GA[(rbase + r) * 300 + col] = f2bf(ax[r]);
                        GB[(rbase + r) * 300 + col] = f2bf(ah[r]);
                    }
                }
            }
        }
        __syncthreads();
        // ---- combine layer 1 ----
        for (int i = tid; i < 6400; i += 256) {
            int row = i / 100, c = i - row * 100;
            float xr = bf2f(GA[row * 300 + c])        + bih1[c];
            float xz = bf2f(GA[row * 300 + 100 + c])  + bih1[100 + c];
            float xn = bf2f(GA[row * 300 + 200 + c])  + bih1[200 + c];
            float hr = bf2f(GB[row * 300 + c])        + bhh1[c];
            float hz = bf2f(GB[row * 300 + 100 + c])  + bhh1[100 + c];
            float hn = bf2f(GB[row * 300 + 200 + c])  + bhh1[200 + c];
            float r  = sigmoidf_(xr + hr);
            float zz = sigmoidf_(xz + hz);
            float ng = tanhf_(xn + r * hn);
            float o  = (1.f - zz) * ng + zz * h1f[i];
            h1f[i] = o;
            h1b[row * 136 + c] = f2bf(o);
        }
        __syncthreads();
    }

    // write final top-layer hidden, bf16 [M][128]
    for (int i = tid; i < 64 * 128; i += 256) {
        int row = i >> 7, c = i & 127;
        int gm = m0 + row;
        if (gm < M)
            hout[(size_t)gm * 128 + c] = (c < 100) ? f2bf(h1f[row * 100 + c]) : (u16)0;
    }
}

// ---------------------------------------------------------------------------
// bf16 MFMA GEMM (Etab build + GAT feature GEMMs)
// ---------------------------------------------------------------------------
#define LDST 40
__global__ __launch_bounds__(256) void gemm_mfma(
    const u16* __restrict__ A, const u16* __restrict__ B,
    float* __restrict__ Cf, u16* __restrict__ Cb,
    int M, int N, int Kt, int lda, int ldw, int ldc)
{
    const int m0 = blockIdx.x * 64;
    if (m0 >= M) return;
    const int n0 = blockIdx.y * 64;

    __shared__ u16 Als[64 * LDST];
    __shared__ u16 Wls[64 * LDST];

    const int tid  = threadIdx.x;
    const int wave = tid >> 6, lane = tid & 63;
    const int row  = tid >> 2, part = (tid & 3) * 8;
    const int fr   = lane & 15, quad = lane >> 4;

    floatx4 acc[4];
#pragma unroll
    for (int t = 0; t < 4; ++t) acc[t] = (floatx4){0.f, 0.f, 0.f, 0.f};

    const int am = m0 + row;  const bool aok = am < M;
    const int wn = n0 + row;  const bool wok = wn < N;
    const uint4 z4 = {0u, 0u, 0u, 0u};

    for (int kk = 0; kk < Kt; ++kk) {
        uint4 av = aok ? *(const uint4*)(A + (size_t)am * lda + kk * 32 + part) : z4;
        uint4 wv = wok ? *(const uint4*)(B + (size_t)wn * ldw + kk * 32 + part) : z4;
        __syncthreads();
        *(uint4*)&Als[row * LDST + part] = av;
        *(uint4*)&Wls[row * LDST + part] = wv;
        __syncthreads();
        short8 af = *(const short8*)&Als[((wave << 4) + fr) * LDST + quad * 8];
#pragma unroll
        for (int t = 0; t < 4; ++t) {
            short8 bf = *(const short8*)&Wls[((t << 4) + fr) * LDST + quad * 8];
            acc[t] = __builtin_amdgcn_mfma_f32_16x16x32_bf16(af, bf, acc[t], 0, 0, 0);
        }
    }

    const int orow0 = m0 + (wave << 4) + quad * 4;
#pragma unroll
    for (int t = 0; t < 4; ++t) {
        int col = n0 + (t << 4) + fr;
        if (col >= N) continue;
#pragma unroll
        for (int r = 0; r < 4; ++r) {
            int mr = orow0 + r;
            if (mr >= M) continue;
            float v = acc[t][r];
            if (Cf) Cf[(size_t)mr * ldc + col] = v;
            if (Cb) Cb[(size_t)mr * ldc + col] = f2bf(v);
        }
    }
}

// ---------------------------------------------------------------------------
// fp32 tiled GEMM (user-embed MLP only)
// ---------------------------------------------------------------------------
__global__ __launch_bounds__(256) void gemm_nt(
    const float* __restrict__ A, const float* __restrict__ W,
    const float* __restrict__ bias, float* __restrict__ C,
    int M, int N, int K, int relu)
{
    const int m0 = blockIdx.x * 64;
    const int n0 = blockIdx.y * 64;
    __shared__ float As[20][68];
    __shared__ float Ws[20][68];
    const int tid = threadIdx.x;
    const int r0 = (tid >> 4) * 4;
    const int c0 = (tid & 15) * 4;
    int sr[5], sk[5];
#pragma unroll
    for (int it = 0; it < 5; ++it) {
        int idx = tid + it * 256;
        sr[it] = idx / 20; sk[it] = idx - sr[it] * 20;
    }
    float acc[4][4];
#pragma unroll
    for (int i = 0; i < 4; ++i)
#pragma unroll
        for (int j = 0; j < 4; ++j) acc[i][j] = 0.f;
    const int nch = (K + 19) / 20;
    for (int ch = 0; ch < nch; ++ch) {
        const int k0 = ch * 20;
#pragma unroll
        for (int it = 0; it < 5; ++it) {
            int m = m0 + sr[it], k = k0 + sk[it];
            float va = 0.f, vw = 0.f;
            if (k < K) {
                if (m < M) va = A[(size_t)m * K + k];
                int n = n0 + sr[it];
                if (n < N) vw = W[(size_t)n * K + k];
            }
            As[sk[it]][sr[it]] = va;
            Ws[sk[it]][sr[it]] = vw;
        }
        __syncthreads();
#pragma unroll
        for (int kkk = 0; kkk < 20; ++kkk) {
            float4 a = *(const float4*)&As[kkk][r0];
            float4 w = *(const float4*)&Ws[kkk][c0];
            float av[4] = {a.x, a.y, a.z, a.w};
            float wv[4] = {w.x, w.y, w.z, w.w};
#pragma unroll
            for (int i = 0; i < 4; ++i)
#pragma unroll
                for (int j = 0; j < 4; ++j)
                    acc[i][j] = fmaf(av[i], wv[j], acc[i][j]);
        }
        __syncthreads();
    }
#pragma unroll
    for (int i = 0; i < 4; ++i) {
        int m = m0 + r0 + i;
        if (m >= M) continue;
#pragma unroll
        for (int j = 0; j < 4; ++j) {
            int n = n0 + c0 + j;
            if (n >= N) continue;
            float v = acc[i][j] + (bias ? bias[n] : 0.f);
            if (relu) v = fmaxf(v, 0.f);
            C[(size_t)m * N + n] = v;
        }
    }
}

// fp32 [M][K] -> bf16 [Mp][ldk], zero-padded rows M..Mp and cols K..ldk
__global__ void convert_pad2(const float* __restrict__ src, u16* __restrict__ dst,
                             int M, int Mp, int K, int ldk)
{
    int t = blockIdx.x * blockDim.x + threadIdx.x;
    if (t >= Mp * ldk) return;
    int n = t / ldk, c = t - n * ldk;
    dst[t] = (n < M && c < K) ? f2bf(src[(size_t)n * K + c]) : (u16)0;
}

// xg (bf16 [NG][128]) = concat(hg[:128], ue, hg[128:])
__global__ void build_xg_bf(const u16* __restrict__ hgb, const float* __restrict__ ue,
                            u16* __restrict__ xgb)
{
    int t = blockIdx.x * blockDim.x + threadIdx.x;
    if (t >= NG * 128) return;
    int n = t >> 7, c = t & 127;
    u16 o = 0;
    if (n < NB)           o = hgb[n * 128 + c];
    else if (n < NB + NU) { if (c < HD) o = f2bf(ue[(size_t)(n - NB) * HD + c]); }
    else                  o = hgb[(size_t)(n - NU) * 128 + c];
    xgb[t] = o;
}

// tree roots: hb rows[0:128) <- xg_final fp32
__global__ void set_roots(const float* __restrict__ src, u16* __restrict__ hb)
{
    int t = blockIdx.x * blockDim.x + threadIdx.x;
    if (t >= NB * HD) return;
    int n = t / HD, c = t - n * HD;
    hb[(size_t)n * 128 + c] = f2bf(src[t]);
}

// ---------------------------------------------------------------------------
// CSR build
// ---------------------------------------------------------------------------
__global__ void csr_count(const int* __restrict__ ei, int E, int N, int* __restrict__ cnt)
{
    int e = blockIdx.x * blockDim.x + threadIdx.x;
    if (e >= E + N) return;
    int dst = (e < E) ? ei[E + e] : e - E;
    atomicAdd(&cnt[dst], 1);
}

__global__ void csr_scan(const int* __restrict__ cnt, int* __restrict__ off,
                         int* __restrict__ cur, int N)
{
    __shared__ int part[256];
    const int tid = threadIdx.x;
    const int per = (N + 255) / 256;
    const int i0 = tid * per;
    const int i1 = min(i0 + per, N);
    int s = 0;
    for (int i = i0; i < i1; ++i) s += cnt[i];
    part[tid] = s;
    __syncthreads();
    for (int o = 1; o < 256; o <<= 1) {
        int u = (tid >= o) ? part[tid - o] : 0;
        __syncthreads();
        part[tid] += u;
        __syncthreads();
    }
    int base = part[tid] - s;   // exclusive prefix of this thread's run
    for (int i = i0; i < i1; ++i) {
        off[i] = base; cur[i] = base;
        base += cnt[i];
    }
    if (tid == 255) off[N] = part[255];
}

__global__ void csr_scatter(const int* __restrict__ ei, int E, int N,
                            int* __restrict__ cur, int* __restrict__ eidx)
{
    int e = blockIdx.x * blockDim.x + threadIdx.x;
    if (e >= E + N) return;
    int dst = (e < E) ? ei[E + e] : e - E;
    int pos = atomicAdd(&cur[dst], 1);
    eidx[pos] = e;
}

// ---------------------------------------------------------------------------
// GAT pieces (feat is bf16)
// ---------------------------------------------------------------------------
__global__ void gat_es_ed(const u16* __restrict__ feat, const float* __restrict__ asrc,
                          const float* __restrict__ adst, float* __restrict__ es,
                          float* __restrict__ ed, int N, int heads, int C)
{
    int gid = blockIdx.x * blockDim.x + threadIdx.x;
    if (gid >= N * heads) return;
    int n = gid / heads, hd = gid - n * heads;
    const u16* hp = feat + ((size_t)n * heads + hd) * C;
    const float* as = asrc + (size_t)hd * C;
    const float* ad = adst + (size_t)hd * C;
    float s1 = 0.f, s2 = 0.f;
    for (int c = 0; c < C; c += 4) {
        uint2 pk = *(const uint2*)(hp + c);
        float v0 = bf2f((u16)(pk.x & 0xffff)), v1 = bf2f((u16)(pk.x >> 16));
        float v2 = bf2f((u16)(pk.y & 0xffff)), v3 = bf2f((u16)(pk.y >> 16));
        s1 += v0 * as[c] + v1 * as[c + 1] + v2 * as[c + 2] + v3 * as[c + 3];
        s2 += v0 * ad[c] + v1 * ad[c + 1] + v2 * ad[c + 2] + v3 * ad[c + 3];
    }
    es[gid] = s1; ed[gid] = s2;
}

__device__ __forceinline__ void atomic_max_f(float* addr, float v)
{
    if (v >= 0.f) atomicMax((int*)addr, __float_as_int(v));
    else          atomicMin((unsigned int*)addr, __float_as_uint(v));
}

__global__ void gat_edge_logit(const int* __restrict__ ei, int E, int N, int heads,
                               const float* __restrict__ es, const float* __restrict__ ed,
                               float* __restrict__ eb, float* __restrict__ m)
{
    int gid = blockIdx.x * blockDim.x + threadIdx.x;
    int EE = E + N;
    if (gid >= EE * heads) return;
    int idx = gid / heads, hd = gid - idx * heads;
    int src, dst;
    if (idx < E) { src = ei[idx]; dst = ei[E + idx]; } else { src = dst = idx - E; }
    float e = es[src * heads + hd] + ed[dst * heads + hd];
    e = e > 0.f ? e : 0.2f * e;
    eb[gid] = e;
    atomic_max_f(&m[dst * heads + hd], e);
}

__global__ void gat_edge_expsum(const int* __restrict__ ei, int E, int N, int heads,
                                float* __restrict__ eb, const float* __restrict__ m,
                                float* __restrict__ s)
{
    int gid = blockIdx.x * blockDim.x + threadIdx.x;
    int EE = E + N;
    if (gid >= EE * heads) return;
    int idx = gid / heads, hd = gid - idx * heads;
    int dst = (idx < E) ? ei[E + idx] : idx - E;
    float e = __expf(eb[gid] - m[dst * heads + hd]);
    eb[gid] = e;
    atomicAdd(&s[dst * heads + hd], e);
}

// per-(dst, chunk) wave gather over bf16 feat; bias+relu fused; dual dtype out
template<int C, int VEC>
__global__ __launch_bounds__(256) void gat_accum_csr(
    const int* __restrict__ off, const int* __restrict__ eidx,
    const int* __restrict__ ei, int E,
    const float* __restrict__ eb, const float* __restrict__ s,
    const u16* __restrict__ feat, const float* __restrict__ bias,
    float* __restrict__ outf, u16* __restrict__ outb,
    int N, int heads, int HC, int nchunk)
{
    int gt = blockIdx.x * blockDim.x + threadIdx.x;
    int w = gt >> 6, lane = gt & 63;
    int dst = w / nchunk, chunk = w - dst * nchunk;
    if (dst >= N) return;
    int c0 = chunk * 64 * VEC + lane * VEC;
    if (c0 >= HC) return;
    int hh[VEC]; float sinv[VEC], acc[VEC];
#pragma unroll
    for (int v = 0; v < VEC; ++v) {
        int c = c0 + v;
        hh[v] = c / C;
        sinv[v] = __fdividef(1.f, s[dst * heads + hh[v]]);
        acc[v] = 0.f;
    }
    int e0 = off[dst], e1 = off[dst + 1];
    for (int p = e0; p < e1; ++p) {
        int j = eidx[p];
        int src = (j < E) ? ei[j] : (j - E);
        const u16* frp = feat + (size_t)src * HC + c0;
        float fv[VEC];
        if (VEC == 4) {
            uint2 pk = *(const uint2*)frp;
            fv[0] = bf2f((u16)(pk.x & 0xffff)); fv[1] = bf2f((u16)(pk.x >> 16));
            fv[2] = bf2f((u16)(pk.y & 0xffff)); fv[3] = bf2f((u16)(pk.y >> 16));
        } else {
            u32 pk = *(const u32*)frp;
            fv[0] = bf2f((u16)(pk & 0xffff)); fv[1] = bf2f((u16)(pk >> 16));
        }
#pragma unroll
        for (int v = 0; v < VEC; ++v)
            acc[v] += fv[v] * eb[(size_t)j * heads + hh[v]] * sinv[v];
    }
#pragma unroll
    for (int v = 0; v < VEC; ++v) {
        int c = c0 + v;
        float o = fmaxf(acc[v] + bias[c], 0.f);
        if (outf) outf[(size_t)dst * HC + c] = o;
        if (outb) outb[(size_t)dst * HC + c] = f2bf(o);
    }
}

__global__ void scatter_mean_accum(const float* __restrict__ x, const int* __restrict__ idx,
                                   float* __restrict__ ssum, float* __restrict__ cnt)
{
    int t = blockIdx.x * blockDim.x + threadIdx.x;
    if (t >= NTREE * HD) return;
    int n = t / HD, c = t - n * HD;
    int b = idx[n];
    atomicAdd(&ssum[b * HD + c], x[t]);
    if (c == 0) atomicAdd(&cnt[b], 1.f);
}

__global__ void fc_out(const float* __restrict__ ssum, const float* __restrict__ cnt,
                       const float* __restrict__ W, const float* __restrict__ b,
                       float* __restrict__ out)
{
    int t = threadIdx.x;                 // 512 threads
    int bb = t >> 2, j = t & 3;
    float inv = __fdividef(1.f, fmaxf(cnt[bb], 1.f));
    float acc = b[j];
    for (int k = 0; k < HD; ++k) acc += ssum[bb * HD + k] * inv * W[j * HD + k];
    out[t] = acc;
}

// ---------------------------------------------------------------------------
// Host launcher
// ---------------------------------------------------------------------------
extern "C" void kernel_launch(void* const* d_in, const int* in_sizes, int n_in,
                              void* d_out, int out_size, void* d_ws, size_t ws_size,
                              hipStream_t stream)
{
    const float* user_feats = (const float*)d_in[1];
    const int*   gnf        = (const int*)d_in[2];
    const int*   gei        = (const int*)d_in[3];
    const int*   tnf        = (const int*)d_in[4];
    const int*   tei        = (const int*)d_in[5];
    const int*   indices    = (const int*)d_in[6];
    const float* h0g        = (const float*)d_in[7];
    const float* h0t        = (const float*)d_in[8];
    const float* temb       = (const float*)d_in[9];
    const float* gW[2][4] = {{(const float*)d_in[10], (const float*)d_in[11], (const float*)d_in[12], (const float*)d_in[13]},
                             {(const float*)d_in[14], (const float*)d_in[15], (const float*)d_in[16], (const float*)d_in[17]}};
    const float* tW[2][4] = {{(const float*)d_in[18], (const float*)d_in[19], (const float*)d_in[20], (const float*)d_in[21]},
                             {(const float*)d_in[22], (const float*)d_in[23], (const float*)d_in[24], (const float*)d_in[25]}};
    const float* uW1 = (const float*)d_in[26]; const float* ub1 = (const float*)d_in[27];
    const float* uW2 = (const float*)d_in[28]; const float* ub2 = (const float*)d_in[29];
    const float* gc1W = (const float*)d_in[30]; const float* gc1as = (const float*)d_in[31];
    const float* gc1ad = (const float*)d_in[32]; const float* gc1b = (const float*)d_in[33];
    const float* gc2W = (const float*)d_in[34]; const float* gc2as = (const float*)d_in[35];
    const float* gc2ad = (const float*)d_in[36]; const float* gc2b = (const float*)d_in[37];
    const float* tc1W = (const float*)d_in[38]; const float* tc1as = (const float*)d_in[39];
    const float* tc1ad = (const float*)d_in[40]; const float* tc1b = (const float*)d_in[41];
    const float* tc2W = (const float*)d_in[42]; const float* tc2as = (const float*)d_in[43];
    const float* tc2ad = (const float*)d_in[44]; const float* tc2b = (const float*)d_in[45];
    const float* fcW = (const float*)d_in[46]; const float* fcb = (const float*)d_in[47];
    float* out = (float*)d_out;

    char* ws = (char*)d_ws;
    const size_t NEED = 224000000;
    if (ws_size < NEED) return;

    // ---- workspace layout (decimal byte offsets) ----
    float* XGF    = (float*)(ws + 0);            // 12 MB   xg_final fp32 [NG][100]
    u16*   TEMB_B = (u16*)(ws + 12000000);       // 12.8 MB [VOC][128]
    u16*   ETAB_B = (u16*)(ws + 25000000);       // 30 MB   [VOC][300]
    u16*   GH1B   = (u16*)(ws + 55000000);       // 2.56 MB [NTG][128]
    u16*   TH1B   = (u16*)(ws + 58000000);       // 7.68 MB [NTREE][128]
    float* UE     = (float*)(ws + 66000000);     // 8 MB
    float* HID    = (float*)(ws + 74000000);     // 8 MB
    u16*   WARENA = (u16*)(ws + 82000000);       // 0.7 MB
    int*   COFF   = (int*)(ws + 83500000);
    int*   CCUR   = (int*)(ws + 83700000);
    int*   CCNT   = (int*)(ws + 83900000);
    int*   CEIDX  = (int*)(ws + 84100000);       // 0.92 MB
    float* ESB    = (float*)(ws + 85100000);
    float* EDB    = (float*)(ws + 86100000);
    float* MB     = (float*)(ws + 87100000);
    float* SB     = (float*)(ws + 88100000);
    float* EBB    = (float*)(ws + 89100000);     // 7.36 MB
    float* SSUM   = (float*)(ws + 96600000);
    float* SCNT   = (float*)(ws + 96800000);
    u16*   XG_B   = (u16*)(ws + 98000000);       // 7.68 MB [NG][128]
    u16*   GFEAT1 = (u16*)(ws + 106000000);      // 30.72 MB [NG][512]
    u16*   GOUT1B = (u16*)(ws + 137000000);      // 30.72 MB [NG][512]
    u16*   GFEAT2 = (u16*)(ws + 168000000);      // 6 MB [NG][100]
    u16*   TFEAT1 = (u16*)(ws + 106000000);      // 48 MB [NTREE][800]  (overlay)
    u16*   TOUT1B = (u16*)(ws + 155000000);      // 48 MB [NTREE][800]  (overlay)
    u16*   TFEAT2 = (u16*)(ws + 204000000);      // 6 MB [NTREE][100]
    float* XOUT2  = (float*)(ws + 211000000);    // 12 MB

    // weight arena slots (u16 element offsets)
    u16* W_HH0 = WARENA;             // [320][128]
    u16* W_IH1 = WARENA + 40960;
    u16* W_HH1 = WARENA + 81920;
    u16* W_IH0 = WARENA + 122880;    // [300][128] (Etab build)
    u16* W_G1  = WARENA + 161280;    // up to [800][128]
    u16* W_G2  = WARENA + 263680;    // up to [100][800]

    auto cvt = [&](const float* src, u16* dst, int M, int Mp, int K, int ldk) {
        convert_pad2<<<((size_t)Mp * ldk + 255) / 256, 256, 0, stream>>>(src, dst, M, Mp, K, ldk);
    };
    auto mfma = [&](const u16* A, int lda, const u16* W, int ldw,
                    float* Cf, u16* Cb, int ldc, int M, int N, int Kt) {
        dim3 grid((M + 63) / 64, (N + 63) / 64, 1);
        gemm_mfma<<<grid, 256, 0, stream>>>(A, W, Cf, Cb, M, N, Kt, lda, ldw, ldc);
    };
    auto csr_build = [&](const int* ei, int E, int N) {
        hipMemsetAsync(CCNT, 0, (size_t)N * 4, stream);
        csr_count<<<(E + N + 255) / 256, 256, 0, stream>>>(ei, E, N, CCNT);
        csr_scan<<<1, 256, 0, stream>>>(CCNT, COFF, CCUR, N);
        csr_scatter<<<(E + N + 255) / 256, 256, 0, stream>>>(ei, E, N, CCUR, CEIDX);
    };
    auto gat_pre = [&](const u16* feat, int N, int heads, int C,
                       const float* asrc, const float* adst, const int* ei, int E) {
        gat_es_ed<<<(N * heads + 255) / 256, 256, 0, stream>>>(feat, asrc, adst, ESB, EDB, N, heads, C);
        hipMemsetAsync(MB, 0xFF, (size_t)N * heads * 4, stream);
        hipMemsetAsync(SB, 0, (size_t)N * heads * 4, stream);
        int EE = E + N;
        gat_edge_logit<<<(EE * heads + 255) / 256, 256, 0, stream>>>(ei, E, N, heads, ESB, EDB, EBB, MB);
        gat_edge_expsum<<<(EE * heads + 255) / 256, 256, 0, stream>>>(ei, E, N, heads, EBB, MB, SB);
    };

    // ---- 1. user embed (fp32) ----
    {
        dim3 g1((NU + 63) / 64, (HD + 63) / 64, 1);
        gemm_nt<<<g1, 256, 0, stream>>>(user_feats, uW1, ub1, HID, NU, HD, 9, 1);
        gemm_nt<<<g1, 256, 0, stream>>>(HID, uW2, ub2, UE, NU, HD, HD, 0);
    }

    // ---- 2. temb -> bf16 ----
    cvt(temb, TEMB_B, VOC, VOC, HD, 128);

    // ---- 3. graph branch ----
    cvt(gW[0][1], W_HH0, 300, 320, HD, 128);
    cvt(gW[1][0], W_IH1, 300, 320, HD, 128);
    cvt(gW[1][1], W_HH1, 300, 320, HD, 128);
    cvt(gW[0][0], W_IH0, 300, 300, HD, 128);
    mfma(TEMB_B, 128, W_IH0, 128, nullptr, ETAB_B, 300, VOC, 300, 4);   // Etab_g

    gru_fused<<<(NTG + 63) / 64, 256, 0, stream>>>(
        ETAB_B, gnf, h0g, W_HH0, W_IH1, W_HH1,
        gW[0][2], gW[0][3], gW[1][2], gW[1][3], GH1B, NTG);

    build_xg_bf<<<(NG * 128 + 255) / 256, 256, 0, stream>>>(GH1B, UE, XG_B);

    csr_build(gei, EG, NG);
    cvt(gc1W, W_G1, 512, 512, HD, 128);
    cvt(gc2W, W_G2, 100, 100, 512, 512);
    {   // graph GAT1: 8 heads x 64
        mfma(XG_B, 128, W_G1, 128, nullptr, GFEAT1, 512, NG, 512, 4);
        gat_pre(GFEAT1, NG, 8, 64, gc1as, gc1ad, gei, EG);
        int waves = NG * 2;
        gat_accum_csr<64, 4><<<(waves + 3) / 4, 256, 0, stream>>>(
            COFF, CEIDX, gei, EG, EBB, SB, GFEAT1, gc1b, nullptr, GOUT1B, NG, 8, 512, 2);
    }
    {   // graph GAT2: 1 head x 100
        mfma(GOUT1B, 512, W_G2, 512, nullptr, GFEAT2, 100, NG, 100, 16);
        gat_pre(GFEAT2, NG, 1, 100, gc2as, gc2ad, gei, EG);
        int waves = NG;
        gat_accum_csr<100, 2><<<(waves + 3) / 4, 256, 0, stream>>>(
            COFF, CEIDX, gei, EG, EBB, SB, GFEAT2, gc2b, XGF, nullptr, NG, 1, 100, 1);
    }

    // ---- 4. tree branch ----
    cvt(tW[0][1], W_HH0, 300, 320, HD, 128);
    cvt(tW[1][0], W_IH1, 300, 320, HD, 128);
    cvt(tW[1][1], W_HH1, 300, 320, HD, 128);
    cvt(tW[0][0], W_IH0, 300, 300, HD, 128);
    mfma(TEMB_B, 128, W_IH0, 128, nullptr, ETAB_B, 300, VOC, 300, 4);   // Etab_t

    gru_fused<<<(NTREE + 63) / 64, 256, 0, stream>>>(
        ETAB_B, tnf, h0t, W_HH0, W_IH1, W_HH1,
        tW[0][2], tW[0][3], tW[1][2], tW[1][3], TH1B, NTREE);

    set_roots<<<(NB * HD + 255) / 256, 256, 0, stream>>>(XGF, TH1B);

    csr_build(tei, ET, NTREE);
    cvt(tc1W, W_G1, 800, 800, HD, 128);
    cvt(tc2W, W_G2, 100, 100, 800, 800);
    {   // tree GAT1: 8 heads x 100
        mfma(TH1B, 128, W_G1, 128, nullptr, TFEAT1, 800, NTREE, 800, 4);
        gat_pre(TFEAT1, NTREE, 8, 100, tc1as, tc1ad, tei, ET);
        int waves = NTREE * 4;
        gat_accum_csr<100, 4><<<(waves + 3) / 4, 256, 0, stream>>>(
            COFF, CEIDX, tei, ET, EBB, SB, TFEAT1, tc1b, nullptr, TOUT1B, NTREE, 8, 800, 4);
    }
    {   // tree GAT2: 1 head x 100
        mfma(TOUT1B, 800, W_G2, 800, nullptr, TFEAT2, 100, NTREE, 100, 25);
        gat_pre(TFEAT2, NTREE, 1, 100, tc2as, tc2ad, tei, ET);
        int waves = NTREE;
        gat_accum_csr<100, 2><<<(waves + 3) / 4, 256, 0, stream>>>(
            COFF, CEIDX, tei, ET, EBB, SB, TFEAT2, tc2b, XOUT2, nullptr, NTREE, 1, 100, 1);
    }

    // ---- 5. scatter_mean + classifier ----
    hipMemsetAsync(SSUM, 0, (size_t)NB * HD * 4, stream);
    hipMemsetAsync(SCNT, 0, (size_t)NB * 4, stream);
    scatter_mean_accum<<<(NTREE * HD + 255) / 256, 256, 0, stream>>>(XOUT2, indices, SSUM, SCNT);
    fc_out<<<1, 512, 0, stream>>>(SSUM, SCNT, fcW, fcb, out);
}

// Round 5
// 2600.961 us; speedup vs baseline: 5.2478x; 1.1890x over previous
//
#include <hip/hip_runtime.h>

// ---------------------------------------------------------------------------
// Problem constants
// ---------------------------------------------------------------------------
#define NB    128
#define HD    100
#define NU    20000
#define NTG   10000
#define NTREE 30000
#define NG    30000
#define TT    20
#define EG    200000
#define ET    60000
#define VOC   50000

typedef unsigned short u16;
typedef unsigned int   u32;
typedef __attribute__((ext_vector_type(8))) short short8;
typedef __attribute__((ext_vector_type(4))) float floatx4;

__device__ __forceinline__ float sigmoidf_(float x) {
    return __fdividef(1.f, 1.f + __expf(-x));
}
__device__ __forceinline__ float tanhf_(float x) {
    return 1.f - __fdividef(2.f, __expf(2.f * x) + 1.f);
}
__device__ __forceinline__ u16 f2bf(float f) {
    u32 u = __float_as_uint(f);
    u32 r = (u + 0x7fffu + ((u >> 16) & 1u)) >> 16;
    return (u16)r;
}
__device__ __forceinline__ float bf2f(u16 h) {
    return __uint_as_float(((u32)h) << 16);
}

// ---------------------------------------------------------------------------
// Fused 2-layer GRU v2: 32 rows/block, h state in registers+LDS(bf16),
// weights streamed from global (L2-hot), Etab gathers batched & issued
// before GEMM0. LDS ~43 KB -> 3 blocks/CU.
// Weights bf16 [320][128] zero-padded. Etab bf16 [VOC][300].
// ---------------------------------------------------------------------------
struct GruProb {
    const u16*   Etab;
    const int*   nodes;
    const float* h0;       // [2][M][100]
    const u16*   Whh0;     // [320][128]
    const u16*   Wih1;
    const u16*   Whh1;
    const float* bih0; const float* bhh0;
    const float* bih1; const float* bhh1;
    u16*         hout;     // [M][128]
    int          M;
};

#define HSTR 136   // LDS h row stride (272 B): 16B-aligned rows, 4-bank rotate

__global__ __launch_bounds__(256) void gru_fused2(GruProb Pg, GruProb Pt, int gblocks)
{
    const bool isg = (int)blockIdx.x < gblocks;
    const GruProb P = isg ? Pg : Pt;
    const int bx = isg ? blockIdx.x : blockIdx.x - gblocks;
    const int M  = P.M;
    const int m0 = bx * 32;

    __shared__ u16 h0b[32 * HSTR];
    __shared__ u16 h1b[32 * HSTR];
    __shared__ u16 GA[32 * 300];
    __shared__ u16 GBn[32 * 100];

    const int tid  = threadIdx.x;
    const int wave = tid >> 6, lane = tid & 63;
    const int fr   = lane & 15, quad = lane >> 4;

    // combine-mapping: thread -> (row, col run)
    const int crow = tid >> 3;
    const int cgm  = m0 + crow;
    const int c0   = (tid & 7) * 13;
    const int L    = (c0 < 100) ? ((100 - c0 < 13) ? (100 - c0) : 13) : 0;
    const bool cok = (cgm < M);

    // h state in registers
    float h0r[13], h1r[13];
#pragma unroll
    for (int j = 0; j < 13; ++j) { h0r[j] = 0.f; h1r[j] = 0.f; }

    // init LDS h (zero-fill then real rows)
    for (int i = tid; i < 32 * HSTR; i += 256) { h0b[i] = 0; h1b[i] = 0; }
    __syncthreads();
    if (cok) {
#pragma unroll
        for (int j = 0; j < 13; ++j) if (j < L) {
            int c = c0 + j;
            float v0 = P.h0[(size_t)cgm * 100 + c];
            float v1 = P.h0[(size_t)(M + cgm) * 100 + c];
            h0r[j] = v0; h1r[j] = v1;
            h0b[crow * HSTR + c] = f2bf(v0);
            h1b[crow * HSTR + c] = f2bf(v1);
        }
    }
    __syncthreads();

    for (int t = 0; t < TT; ++t) {
        // ---- issue Etab gathers for this step (complete under GEMM0) ----
        u16 xrv[13], xzv[13], xnv[13];
        {
            int nd = cok ? P.nodes[(size_t)cgm * TT + t] : 0;
            const u16* ex = P.Etab + (size_t)nd * 300 + c0;
#pragma unroll
            for (int j = 0; j < 13; ++j) if (j < L) {
                xrv[j] = ex[j];
                xzv[j] = ex[100 + j];
                xnv[j] = ex[200 + j];
            }
        }

        // ---- GEMM0: Gh0 = h0b @ Whh0^T -> GA ----
#pragma unroll
        for (int rt = 0; rt < 2; ++rt) {
            short8 a[4];
#pragma unroll
            for (int kk = 0; kk < 4; ++kk)
                a[kk] = *(const short8*)&h0b[(rt * 16 + fr) * HSTR + kk * 32 + quad * 8];
#pragma unroll
            for (int s = 0; s < 5; ++s) {
                int ct = wave + 4 * s;
                const u16* bp = P.Whh0 + (size_t)(ct * 16 + fr) * 128 + quad * 8;
                floatx4 acc = {0.f, 0.f, 0.f, 0.f};
#pragma unroll
                for (int kk = 0; kk < 4; ++kk)
                    acc = __builtin_amdgcn_mfma_f32_16x16x32_bf16(
                        a[kk], *(const short8*)(bp + kk * 32), acc, 0, 0, 0);
                int col = ct * 16 + fr;
                if (col < 300) {
                    int rbase = rt * 16 + quad * 4;
#pragma unroll
                    for (int r = 0; r < 4; ++r)
                        GA[(rbase + r) * 300 + col] = f2bf(acc[r]);
                }
            }
        }
        __syncthreads();

        // ---- combine layer 0 ----
        if (cok) {
#pragma unroll
            for (int j = 0; j < 13; ++j) if (j < L) {
                int c = c0 + j;
                float xr = bf2f(xrv[j]) + P.bih0[c];
                float xz = bf2f(xzv[j]) + P.bih0[100 + c];
                float xn = bf2f(xnv[j]) + P.bih0[200 + c];
                float hr = bf2f(GA[crow * 300 + c])       + P.bhh0[c];
                float hz = bf2f(GA[crow * 300 + 100 + c]) + P.bhh0[100 + c];
                float hn = bf2f(GA[crow * 300 + 200 + c]) + P.bhh0[200 + c];
                float r  = sigmoidf_(xr + hr);
                float zz = sigmoidf_(xz + hz);
                float ng = tanhf_(xn + r * hn);
                float o  = (1.f - zz) * ng + zz * h0r[j];
                h0r[j] = o;
                h0b[crow * HSTR + c] = f2bf(o);
            }
        }
        __syncthreads();

        // ---- GEMM1: Gx1 = h0b@Wih1^T, Gh1 = h1b@Whh1^T ----
        // r,z cols (<200): store sum; n cols: xn->GA, hn->GBn
#pragma unroll
        for (int rt = 0; rt < 2; ++rt) {
            short8 a0[4], a1[4];
#pragma unroll
            for (int kk = 0; kk < 4; ++kk) {
                a0[kk] = *(const short8*)&h0b[(rt * 16 + fr) * HSTR + kk * 32 + quad * 8];
                a1[kk] = *(const short8*)&h1b[(rt * 16 + fr) * HSTR + kk * 32 + quad * 8];
            }
#pragma unroll
            for (int s = 0; s < 5; ++s) {
                int ct = wave + 4 * s;
                const u16* bpx = P.Wih1 + (size_t)(ct * 16 + fr) * 128 + quad * 8;
                const u16* bph = P.Whh1 + (size_t)(ct * 16 + fr) * 128 + quad * 8;
                floatx4 ax = {0.f, 0.f, 0.f, 0.f};
                floatx4 ah = {0.f, 0.f, 0.f, 0.f};
#pragma unroll
                for (int kk = 0; kk < 4; ++kk) {
                    ax = __builtin_amdgcn_mfma_f32_16x16x32_bf16(
                        a0[kk], *(const short8*)(bpx + kk * 32), ax, 0, 0, 0);
                    ah = __builtin_amdgcn_mfma_f32_16x16x32_bf16(
                        a1[kk], *(const short8*)(bph + kk * 32), ah, 0, 0, 0);
                }
                int col = ct * 16 + fr;
                if (col < 300) {
                    int rbase = rt * 16 + quad * 4;
                    if (col < 200) {
#pragma unroll
                        for (int r = 0; r < 4; ++r)
                            GA[(rbase + r) * 300 + col] = f2bf(ax[r] + ah[r]);
                    } else {
#pragma unroll
                        for (int r = 0; r < 4; ++r) {
                            GA[(rbase + r) * 300 + col] = f2bf(ax[r]);
                            GBn[(rbase + r) * 100 + col - 200] = f2bf(ah[r]);
                        }
                    }
                }
            }
        }
        __syncthreads();

        // ---- combine layer 1 ----
        if (cok) {
#pragma unroll
            for (int j = 0; j < 13; ++j) if (j < L) {
                int c = c0 + j;
                float sr_ = bf2f(GA[crow * 300 + c]);
                float sz_ = bf2f(GA[crow * 300 + 100 + c]);
                float xn_ = bf2f(GA[crow * 300 + 200 + c]);
                float hn_ = bf2f(GBn[crow * 100 + c]);
                float r  = sigmoidf_(sr_ + P.bih1[c] + P.bhh1[c]);
                float zz = sigmoidf_(sz_ + P.bih1[100 + c] + P.bhh1[100 + c]);
                float ng = tanhf_(xn_ + P.bih1[200 + c] + r * (hn_ + P.bhh1[200 + c]));
                float o  = (1.f - zz) * ng + zz * h1r[j];
                h1r[j] = o;
                h1b[crow * HSTR + c] = f2bf(o);
            }
        }
        __syncthreads();
    }

    // ---- write final top-layer hidden, bf16 [M][128] ----
    for (int i = tid; i < 32 * 128; i += 256) {
        int row = i >> 7, c = i & 127;
        int gm = m0 + row;
        if (gm < M)
            P.hout[(size_t)gm * 128 + c] = (c < 100) ? h1b[row * HSTR + c] : (u16)0;
    }
}

// ---------------------------------------------------------------------------
// bf16 MFMA GEMM (Etab build + GAT feature GEMMs)
// ---------------------------------------------------------------------------
#define LDST 40
__global__ __launch_bounds__(256) void gemm_mfma(
    const u16* __restrict__ A, const u16* __restrict__ B,
    float* __restrict__ Cf, u16* __restrict__ Cb,
    int M, int N, int Kt, int lda, int ldw, int ldc)
{
    const int m0 = blockIdx.x * 64;
    if (m0 >= M) return;
    const int n0 = blockIdx.y * 64;

    __shared__ u16 Als[64 * LDST];
    __shared__ u16 Wls[64 * LDST];

    const int tid  = threadIdx.x;
    const int wave = tid >> 6, lane = tid & 63;
    const int row  = tid >> 2, part = (tid & 3) * 8;
    const int fr   = lane & 15, quad = lane >> 4;

    floatx4 acc[4];
#pragma unroll
    for (int t = 0; t < 4; ++t) acc[t] = (floatx4){0.f, 0.f, 0.f, 0.f};

    const int am = m0 + row;  const bool aok = am < M;
    const int wn = n0 + row;  const bool wok = wn < N;
    const uint4 z4 = {0u, 0u, 0u, 0u};

    for (int kk = 0; kk < Kt; ++kk) {
        uint4 av = aok ? *(const uint4*)(A + (size_t)am * lda + kk * 32 + part) : z4;
        uint4 wv = wok ? *(const uint4*)(B + (size_t)wn * ldw + kk * 32 + part) : z4;
        __syncthreads();
        *(uint4*)&Als[row * LDST + part] = av;
        *(uint4*)&Wls[row * LDST + part] = wv;
        __syncthreads();
        short8 af = *(const short8*)&Als[((wave << 4) + fr) * LDST + quad * 8];
#pragma unroll
        for (int t = 0; t < 4; ++t) {
            short8 bf = *(const short8*)&Wls[((t << 4) + fr) * LDST + quad * 8];
            acc[t] = __builtin_amdgcn_mfma_f32_16x16x32_bf16(af, bf, acc[t], 0, 0, 0);
        }
    }

    const int orow0 = m0 + (wave << 4) + quad * 4;
#pragma unroll
    for (int t = 0; t < 4; ++t) {
        int col = n0 + (t << 4) + fr;
        if (col >= N) continue;
#pragma unroll
        for (int r = 0; r < 4; ++r) {
            int mr = orow0 + r;
            if (mr >= M) continue;
            float v = acc[t][r];
            if (Cf) Cf[(size_t)mr * ldc + col] = v;
            if (Cb) Cb[(size_t)mr * ldc + col] = f2bf(v);
        }
    }
}

// ---------------------------------------------------------------------------
// fp32 tiled GEMM (user-embed MLP only)
// ---------------------------------------------------------------------------
__global__ __launch_bounds__(256) void gemm_nt(
    const float* __restrict__ A, const float* __restrict__ W,
    const float* __restrict__ bias, float* __restrict__ C,
    int M, int N, int K, int relu)
{
    const int m0 = blockIdx.x * 64;
    const int n0 = blockIdx.y * 64;
    __shared__ float As[20][68];
    __shared__ float Ws[20][68];
    const int tid = threadIdx.x;
    const int r0 = (tid >> 4) * 4;
    const int c0 = (tid & 15) * 4;
    int sr[5], sk[5];
#pragma unroll
    for (int it = 0; it < 5; ++it) {
        int idx = tid + it * 256;
        sr[it] = idx / 20; sk[it] = idx - sr[it] * 20;
    }
    float acc[4][4];
#pragma unroll
    for (int i = 0; i < 4; ++i)
#pragma unroll
        for (int j = 0; j < 4; ++j) acc[i][j] = 0.f;
    const int nch = (K + 19) / 20;
    for (int ch = 0; ch < nch; ++ch) {
        const int k0 = ch * 20;
#pragma unroll
        for (int it = 0; it < 5; ++it) {
            int m = m0 + sr[it], k = k0 + sk[it];
            float va = 0.f, vw = 0.f;
            if (k < K) {
                if (m < M) va = A[(size_t)m * K + k];
                int n = n0 + sr[it];
                if (n < N) vw = W[(size_t)n * K + k];
            }
            As[sk[it]][sr[it]] = va;
            Ws[sk[it]][sr[it]] = vw;
        }
        __syncthreads();
#pragma unroll
        for (int kkk = 0; kkk < 20; ++kkk) {
            float4 a = *(const float4*)&As[kkk][r0];
            float4 w = *(const float4*)&Ws[kkk][c0];
            float av[4] = {a.x, a.y, a.z, a.w};
            float wv[4] = {w.x, w.y, w.z, w.w};
#pragma unroll
            for (int i = 0; i < 4; ++i)
#pragma unroll
                for (int j = 0; j < 4; ++j)
                    acc[i][j] = fmaf(av[i], wv[j], acc[i][j]);
        }
        __syncthreads();
    }
#pragma unroll
    for (int i = 0; i < 4; ++i) {
        int m = m0 + r0 + i;
        if (m >= M) continue;
#pragma unroll
        for (int j = 0; j < 4; ++j) {
            int n = n0 + c0 + j;
            if (n >= N) continue;
            float v = acc[i][j] + (bias ? bias[n] : 0.f);
            if (relu) v = fmaxf(v, 0.f);
            C[(size_t)m * N + n] = v;
        }
    }
}

// fp32 [M][K] -> bf16 [Mp][ldk], zero-padded rows M..Mp and cols K..ldk
__global__ void convert_pad2(const float* __restrict__ src, u16* __restrict__ dst,
                             int M, int Mp, int K, int ldk)
{
    int t = blockIdx.x * blockDim.x + threadIdx.x;
    if (t >= Mp * ldk) return;
    int n = t / ldk, c = t - n * ldk;
    dst[t] = (n < M && c < K) ? f2bf(src[(size_t)n * K + c]) : (u16)0;
}

// xg (bf16 [NG][128]) = concat(hg[:128], ue, hg[128:])
__global__ void build_xg_bf(const u16* __restrict__ hgb, const float* __restrict__ ue,
                            u16* __restrict__ xgb)
{
    int t = blockIdx.x * blockDim.x + threadIdx.x;
    if (t >= NG * 128) return;
    int n = t >> 7, c = t & 127;
    u16 o = 0;
    if (n < NB)           o = hgb[n * 128 + c];
    else if (n < NB + NU) { if (c < HD) o = f2bf(ue[(size_t)(n - NB) * HD + c]); }
    else                  o = hgb[(size_t)(n - NU) * 128 + c];
    xgb[t] = o;
}

// tree roots: hb rows[0:128) <- xg_final fp32
__global__ void set_roots(const float* __restrict__ src, u16* __restrict__ hb)
{
    int t = blockIdx.x * blockDim.x + threadIdx.x;
    if (t >= NB * HD) return;
    int n = t / HD, c = t - n * HD;
    hb[(size_t)n * 128 + c] = f2bf(src[t]);
}

// ---------------------------------------------------------------------------
// CSR build
// ---------------------------------------------------------------------------
__global__ void csr_count(const int* __restrict__ ei, int E, int N, int* __restrict__ cnt)
{
    int e = blockIdx.x * blockDim.x + threadIdx.x;
    if (e >= E + N) return;
    int dst = (e < E) ? ei[E + e] : e - E;
    atomicAdd(&cnt[dst], 1);
}

__global__ void csr_scan(const int* __restrict__ cnt, int* __restrict__ off,
                         int* __restrict__ cur, int N)
{
    __shared__ int part[256];
    const int tid = threadIdx.x;
    const int per = (N + 255) / 256;
    const int i0 = tid * per;
    const int i1 = min(i0 + per, N);
    int s = 0;
    for (int i = i0; i < i1; ++i) s += cnt[i];
    part[tid] = s;
    __syncthreads();
    for (int o = 1; o < 256; o <<= 1) {
        int u = (tid >= o) ? part[tid - o] : 0;
        __syncthreads();
        part[tid] += u;
        __syncthreads();
    }
    int base = part[tid] - s;
    for (int i = i0; i < i1; ++i) {
        off[i] = base; cur[i] = base;
        base += cnt[i];
    }
    if (tid == 255) off[N] = part[255];
}

__global__ void csr_scatter(const int* __restrict__ ei, int E, int N,
                            int* __restrict__ cur, int* __restrict__ eidx)
{
    int e = blockIdx.x * blockDim.x + threadIdx.x;
    if (e >= E + N) return;
    int dst = (e < E) ? ei[E + e] : e - E;
    int pos = atomicAdd(&cur[dst], 1);
    eidx[pos] = e;
}

// ---------------------------------------------------------------------------
// GAT pieces (feat is bf16)
// ---------------------------------------------------------------------------
__global__ void gat_es_ed(const u16* __restrict__ feat, const float* __restrict__ asrc,
                          const float* __restrict__ adst, float* __restrict__ es,
                          float* __restrict__ ed, int N, int heads, int C)
{
    int gid = blockIdx.x * blockDim.x + threadIdx.x;
    if (gid >= N * heads) return;
    int n = gid / heads, hd = gid - n * heads;
    const u16* hp = feat + ((size_t)n * heads + hd) * C;
    const float* as = asrc + (size_t)hd * C;
    const float* ad = adst + (size_t)hd * C;
    float s1 = 0.f, s2 = 0.f;
    for (int c = 0; c < C; c += 4) {
        uint2 pk = *(const uint2*)(hp + c);
        float v0 = bf2f((u16)(pk.x & 0xffff)), v1 = bf2f((u16)(pk.x >> 16));
        float v2 = bf2f((u16)(pk.y & 0xffff)), v3 = bf2f((u16)(pk.y >> 16));
        s1 += v0 * as[c] + v1 * as[c + 1] + v2 * as[c + 2] + v3 * as[c + 3];
        s2 += v0 * ad[c] + v1 * ad[c + 1] + v2 * ad[c + 2] + v3 * ad[c + 3];
    }
    es[gid] = s1; ed[gid] = s2;
}

__device__ __forceinline__ void atomic_max_f(float* addr, float v)
{
    if (v >= 0.f) atomicMax((int*)addr, __float_as_int(v));
    else          atomicMin((unsigned int*)addr, __float_as_uint(v));
}

__global__ void gat_edge_logit(const int* __restrict__ ei, int E, int N, int heads,
                               const float* __restrict__ es, const float* __restrict__ ed,
                               float* __restrict__ eb, float* __restrict__ m)
{
    int gid = blockIdx.x * blockDim.x + threadIdx.x;
    int EE = E + N;
    if (gid >= EE * heads) return;
    int idx = gid / heads, hd = gid - idx * heads;
    int src, dst;
    if (idx < E) { src = ei[idx]; dst = ei[E + idx]; } else { src = dst = idx - E; }
    float e = es[src * heads + hd] + ed[dst * heads + hd];
    e = e > 0.f ? e : 0.2f * e;
    eb[gid] = e;
    atomic_max_f(&m[dst * heads + hd], e);
}

__global__ void gat_edge_expsum(const int* __restrict__ ei, int E, int N, int heads,
                                float* __restrict__ eb, const float* __restrict__ m,
                                float* __restrict__ s)
{
    int gid = blockIdx.x * blockDim.x + threadIdx.x;
    int EE = E + N;
    if (gid >= EE * heads) return;
    int idx = gid / heads, hd = gid - idx * heads;
    int dst = (idx < E) ? ei[E + idx] : idx - E;
    float e = __expf(eb[gid] - m[dst * heads + hd]);
    eb[gid] = e;
    atomicAdd(&s[dst * heads + hd], e);
}

// per-(dst, chunk) wave gather over bf16 feat; bias+relu fused; dual dtype out
template<int C, int VEC>
__global__ __launch_bounds__(256) void gat_accum_csr(
    const int* __restrict__ off, const int* __restrict__ eidx,
    const int* __restrict__ ei, int E,
    const float* __restrict__ eb, const float* __restrict__ s,
    const u16* __restrict__ feat, const float* __restrict__ bias,
    float* __restrict__ outf, u16* __restrict__ outb,
    int N, int heads, int HC, int nchunk)
{
    int gt = blockIdx.x * blockDim.x + threadIdx.x;
    int w = gt >> 6, lane = gt & 63;
    int dst = w / nchunk, chunk = w - dst * nchunk;
    if (dst >= N) return;
    int c0 = chunk * 64 * VEC + lane * VEC;
    if (c0 >= HC) return;
    int hh[VEC]; float sinv[VEC], acc[VEC];
#pragma unroll
    for (int v = 0; v < VEC; ++v) {
        int c = c0 + v;
        hh[v] = c / C;
        sinv[v] = __fdividef(1.f, s[dst * heads + hh[v]]);
        acc[v] = 0.f;
    }
    int e0 = off[dst], e1 = off[dst + 1];
    for (int p = e0; p < e1; ++p) {
        int j = eidx[p];
        int src = (j < E) ? ei[j] : (j - E);
        const u16* frp = feat + (size_t)src * HC + c0;
        float fv[VEC];
        if (VEC == 4) {
            uint2 pk = *(const uint2*)frp;
            fv[0] = bf2f((u16)(pk.x & 0xffff)); fv[1] = bf2f((u16)(pk.x >> 16));
            fv[2] = bf2f((u16)(pk.y & 0xffff)); fv[3] = bf2f((u16)(pk.y >> 16));
        } else {
            u32 pk = *(const u32*)frp;
            fv[0] = bf2f((u16)(pk & 0xffff)); fv[1] = bf2f((u16)(pk >> 16));
        }
#pragma unroll
        for (int v = 0; v < VEC; ++v)
            acc[v] += fv[v] * eb[(size_t)j * heads + hh[v]] * sinv[v];
    }
#pragma unroll
    for (int v = 0; v < VEC; ++v) {
        int c = c0 + v;
        float o = fmaxf(acc[v] + bias[c], 0.f);
        if (outf) outf[(size_t)dst * HC + c] = o;
        if (outb) outb[(size_t)dst * HC + c] = f2bf(o);
    }
}

__global__ void scatter_mean_accum(const float* __restrict__ x, const int* __restrict__ idx,
                                   float* __restrict__ ssum, float* __restrict__ cnt)
{
    int t = blockIdx.x * blockDim.x + threadIdx.x;
    if (t >= NTREE * HD) return;
    int n = t / HD, c = t - n * HD;
    int b = idx[n];
    atomicAdd(&ssum[b * HD + c], x[t]);
    if (c == 0) atomicAdd(&cnt[b], 1.f);
}

__global__ void fc_out(const float* __restrict__ ssum, const float* __restrict__ cnt,
                       const float* __restrict__ W, const float* __restrict__ b,
                       float* __restrict__ out)
{
    int t = threadIdx.x;                 // 512 threads
    int bb = t >> 2, j = t & 3;
    float inv = __fdividef(1.f, fmaxf(cnt[bb], 1.f));
    float acc = b[j];
    for (int k = 0; k < HD; ++k) acc += ssum[bb * HD + k] * inv * W[j * HD + k];
    out[t] = acc;
}

// ---------------------------------------------------------------------------
// Host launcher
// ---------------------------------------------------------------------------
extern "C" void kernel_launch(void* const* d_in, const int* in_sizes, int n_in,
                              void* d_out, int out_size, void* d_ws, size_t ws_size,
                              hipStream_t stream)
{
    const float* user_feats = (const float*)d_in[1];
    const int*   gnf        = (const int*)d_in[2];
    const int*   gei        = (const int*)d_in[3];
    const int*   tnf        = (const int*)d_in[4];
    const int*   tei        = (const int*)d_in[5];
    const int*   indices    = (const int*)d_in[6];
    const float* h0g        = (const float*)d_in[7];
    const float* h0t        = (const float*)d_in[8];
    const float* temb       = (const float*)d_in[9];
    const float* gW[2][4] = {{(const float*)d_in[10], (const float*)d_in[11], (const float*)d_in[12], (const float*)d_in[13]},
                             {(const float*)d_in[14], (const float*)d_in[15], (const float*)d_in[16], (const float*)d_in[17]}};
    const float* tW[2][4] = {{(const float*)d_in[18], (const float*)d_in[19], (const float*)d_in[20], (const float*)d_in[21]},
                             {(const float*)d_in[22], (const float*)d_in[23], (const float*)d_in[24], (const float*)d_in[25]}};
    const float* uW1 = (const float*)d_in[26]; const float* ub1 = (const float*)d_in[27];
    const float* uW2 = (const float*)d_in[28]; const float* ub2 = (const float*)d_in[29];
    const float* gc1W = (const float*)d_in[30]; const float* gc1as = (const float*)d_in[31];
    const float* gc1ad = (const float*)d_in[32]; const float* gc1b = (const float*)d_in[33];
    const float* gc2W = (const float*)d_in[34]; const float* gc2as = (const float*)d_in[35];
    const float* gc2ad = (const float*)d_in[36]; const float* gc2b = (const float*)d_in[37];
    const float* tc1W = (const float*)d_in[38]; const float* tc1as = (const float*)d_in[39];
    const float* tc1ad = (const float*)d_in[40]; const float* tc1b = (const float*)d_in[41];
    const float* tc2W = (const float*)d_in[42]; const float* tc2as = (const float*)d_in[43];
    const float* tc2ad = (const float*)d_in[44]; const float* tc2b = (const float*)d_in[45];
    const float* fcW = (const float*)d_in[46]; const float* fcb = (const float*)d_in[47];
    float* out = (float*)d_out;

    char* ws = (char*)d_ws;
    const size_t NEED = 227000000;
    if (ws_size < NEED) return;

    // ---- workspace layout (decimal byte offsets) ----
    float* XGF    = (float*)(ws + 0);            // 12 MB xg_final fp32 [NG][100]
    u16*   TEMB_B = (u16*)(ws + 12000000);       // 12.8 MB [VOC][128]
    u16*   ETAB_G = (u16*)(ws + 25000000);       // 30 MB [VOC][300]
    u16*   ETAB_T = (u16*)(ws + 55000000);       // 30 MB
    u16*   GH1B   = (u16*)(ws + 85000000);       // 2.56 MB [NTG][128]
    u16*   TH1B   = (u16*)(ws + 88000000);       // 7.68 MB [NTREE][128]
    float* UE     = (float*)(ws + 96000000);     // 8 MB
    float* HID    = (float*)(ws + 104000000);    // 8 MB
    u16*   WARENA = (u16*)(ws + 112000000);      // ~0.94 MB
    int*   GOFF   = (int*)(ws + 113200000);
    int*   GCUR   = (int*)(ws + 113400000);
    int*   GCNT   = (int*)(ws + 113600000);
    int*   GEIDX  = (int*)(ws + 113800000);      // 0.92 MB
    int*   TOFF   = (int*)(ws + 114800000);
    int*   TCUR   = (int*)(ws + 115000000);
    int*   TCNT   = (int*)(ws + 115200000);
    int*   TEIDX  = (int*)(ws + 115400000);      // 0.36 MB
    float* ESB    = (float*)(ws + 115800000);
    float* EDB    = (float*)(ws + 116800000);
    float* MB     = (float*)(ws + 117800000);
    float* SB     = (float*)(ws + 118800000);
    float* EBB    = (float*)(ws + 119800000);    // 7.36 MB
    float* SSUM   = (float*)(ws + 127200000);
    float* SCNT   = (float*)(ws + 127300000);
    u16*   XG_B   = (u16*)(ws + 128000000);      // 7.68 MB [NG][128]
    u16*   GFEAT1 = (u16*)(ws + 136000000);      // 30.72 MB [NG][512]
    u16*   GOUT1B = (u16*)(ws + 167000000);      // 30.72 MB
    u16*   GFEAT2 = (u16*)(ws + 198000000);      // 6 MB [NG][100]
    u16*   TFEAT1 = (u16*)(ws + 136000000);      // 48 MB [NTREE][800] (overlay)
    u16*   TOUT1B = (u16*)(ws + 25000000);       // 48 MB (overlay: Etabs dead)
    u16*   TFEAT2 = (u16*)(ws + 198000000);      // 6 MB (overlay)
    float* XOUT2  = (float*)(ws + 205000000);    // 12 MB -> 217 MB

    // weight arena slots (u16 element offsets)
    u16* gWHH0 = WARENA + 0;         // [320][128]
    u16* gWIH1 = WARENA + 40960;
    u16* gWHH1 = WARENA + 81920;
    u16* tWHH0 = WARENA + 122880;
    u16* tWIH1 = WARENA + 163840;
    u16* tWHH1 = WARENA + 204800;
    u16* W_IH0 = WARENA + 245760;    // [300][128] scratch for Etab builds
    u16* W_G1  = WARENA + 284160;    // up to [800][128]
    u16* W_G2  = WARENA + 386560;    // up to [100][800]

    auto cvt = [&](const float* src, u16* dst, int M, int Mp, int K, int ldk) {
        convert_pad2<<<((size_t)Mp * ldk + 255) / 256, 256, 0, stream>>>(src, dst, M, Mp, K, ldk);
    };
    auto mfma = [&](const u16* A, int lda, const u16* W, int ldw,
                    float* Cf, u16* Cb, int ldc, int M, int N, int Kt) {
        dim3 grid((M + 63) / 64, (N + 63) / 64, 1);
        gemm_mfma<<<grid, 256, 0, stream>>>(A, W, Cf, Cb, M, N, Kt, lda, ldw, ldc);
    };
    auto csr_build = [&](const int* ei, int E, int N, int* cnt, int* off, int* cur, int* eidx) {
        hipMemsetAsync(cnt, 0, (size_t)N * 4, stream);
        csr_count<<<(E + N + 255) / 256, 256, 0, stream>>>(ei, E, N, cnt);
        csr_scan<<<1, 256, 0, stream>>>(cnt, off, cur, N);
        csr_scatter<<<(E + N + 255) / 256, 256, 0, stream>>>(ei, E, N, cur, eidx);
    };
    auto gat_pre = [&](const u16* feat, int N, int heads, int C,
                       const float* asrc, const float* adst, const int* ei, int E) {
        gat_es_ed<<<(N * heads + 255) / 256, 256, 0, stream>>>(feat, asrc, adst, ESB, EDB, N, heads, C);
        hipMemsetAsync(MB, 0xFF, (size_t)N * heads * 4, stream);
        hipMemsetAsync(SB, 0, (size_t)N * heads * 4, stream);
        int EE = E + N;
        gat_edge_logit<<<(EE * heads + 255) / 256, 256, 0, stream>>>(ei, E, N, heads, ESB, EDB, EBB, MB);
        gat_edge_expsum<<<(EE * heads + 255) / 256, 256, 0, stream>>>(ei, E, N, heads, EBB, MB, SB);
    };

    // ---- 1. user embed (fp32) ----
    {
        dim3 g1((NU + 63) / 64, (HD + 63) / 64, 1);
        gemm_nt<<<g1, 256, 0, stream>>>(user_feats, uW1, ub1, HID, NU, HD, 9, 1);
        gemm_nt<<<g1, 256, 0, stream>>>(HID, uW2, ub2, UE, NU, HD, HD, 0);
    }

    // ---- 2. converts + Etab builds (both branches) ----
    cvt(temb, TEMB_B, VOC, VOC, HD, 128);
    cvt(gW[0][1], gWHH0, 300, 320, HD, 128);
    cvt(gW[1][0], gWIH1, 300, 320, HD, 128);
    cvt(gW[1][1], gWHH1, 300, 320, HD, 128);
    cvt(tW[0][1], tWHH0, 300, 320, HD, 128);
    cvt(tW[1][0], tWIH1, 300, 320, HD, 128);
    cvt(tW[1][1], tWHH1, 300, 320, HD, 128);
    cvt(gW[0][0], W_IH0, 300, 300, HD, 128);
    mfma(TEMB_B, 128, W_IH0, 128, nullptr, ETAB_G, 300, VOC, 300, 4);
    cvt(tW[0][0], W_IH0, 300, 300, HD, 128);
    mfma(TEMB_B, 128, W_IH0, 128, nullptr, ETAB_T, 300, VOC, 300, 4);

    // CSR for both graphs (independent)
    csr_build(gei, EG, NG, GCNT, GOFF, GCUR, GEIDX);
    csr_build(tei, ET, NTREE, TCNT, TOFF, TCUR, TEIDX);

    // ---- 3. combined two-branch GRU ----
    {
        GruProb Pg = { ETAB_G, gnf, h0g, gWHH0, gWIH1, gWHH1,
                       gW[0][2], gW[0][3], gW[1][2], gW[1][3], GH1B, NTG };
        GruProb Pt = { ETAB_T, tnf, h0t, tWHH0, tWIH1, tWHH1,
                       tW[0][2], tW[0][3], tW[1][2], tW[1][3], TH1B, NTREE };
        int gblocks = (NTG + 31) / 32;
        int tblocks = (NTREE + 31) / 32;
        gru_fused2<<<gblocks + tblocks, 256, 0, stream>>>(Pg, Pt, gblocks);
    }

    // ---- 4. graph GAT chain ----
    build_xg_bf<<<(NG * 128 + 255) / 256, 256, 0, stream>>>(GH1B, UE, XG_B);
    cvt(gc1W, W_G1, 512, 512, HD, 128);
    cvt(gc2W, W_G2, 100, 100, 512, 512);
    {   // graph GAT1: 8 heads x 64
        mfma(XG_B, 128, W_G1, 128, nullptr, GFEAT1, 512, NG, 512, 4);
        gat_pre(GFEAT1, NG, 8, 64, gc1as, gc1ad, gei, EG);
        int waves = NG * 2;
        gat_accum_csr<64, 4><<<(waves + 3) / 4, 256, 0, stream>>>(
            GOFF, GEIDX, gei, EG, EBB, SB, GFEAT1, gc1b, nullptr, GOUT1B, NG, 8, 512, 2);
    }
    {   // graph GAT2: 1 head x 100
        mfma(GOUT1B, 512, W_G2, 512, nullptr, GFEAT2, 100, NG, 100, 16);
        gat_pre(GFEAT2, NG, 1, 100, gc2as, gc2ad, gei, EG);
        int waves = NG;
        gat_accum_csr<100, 2><<<(waves + 3) / 4, 256, 0, stream>>>(
            GOFF, GEIDX, gei, EG, EBB, SB, GFEAT2, gc2b, XGF, nullptr, NG, 1, 100, 1);
    }

    // ---- 5. tree GAT chain ----
    set_roots<<<(NB * HD + 255) / 256, 256, 0, stream>>>(XGF, TH1B);
    cvt(tc1W, W_G1, 800, 800, HD, 128);
    cvt(tc2W, W_G2, 100, 100, 800, 800);
    {   // tree GAT1: 8 heads x 100
        mfma(TH1B, 128, W_G1, 128, nullptr, TFEAT1, 800, NTREE, 800, 4);
        gat_pre(TFEAT1, NTREE, 8, 100, tc1as, tc1ad, tei, ET);
        int waves = NTREE * 4;
        gat_accum_csr<100, 4><<<(waves + 3) / 4, 256, 0, stream>>>(
            TOFF, TEIDX, tei, ET, EBB, SB, TFEAT1, tc1b, nullptr, TOUT1B, NTREE, 8, 800, 4);
    }
    {   // tree GAT2: 1 head x 100
        mfma(TOUT1B, 800, W_G2, 800, nullptr, TFEAT2, 100, NTREE, 100, 25);
        gat_pre(TFEAT2, NTREE, 1, 100, tc2as, tc2ad, tei, ET);
        int waves = NTREE;
        gat_accum_csr<100, 2><<<(waves + 3) / 4, 256, 0, stream>>>(
            TOFF, TEIDX, tei, ET, EBB, SB, TFEAT2, tc2b, XOUT2, nullptr, NTREE, 1, 100, 1);
    }

    // ---- 6. scatter_mean + classifier ----
    hipMemsetAsync(SSUM, 0, (size_t)NB * HD * 4, stream);
    hipMemsetAsync(SCNT, 0, (size_t)NB * 4, stream);
    scatter_mean_accum<<<(NTREE * HD + 255) / 256, 256, 0, stream>>>(XOUT2, indices, SSUM, SCNT);
    fc_out<<<1, 512, 0, stream>>>(SSUM, SCNT, fcW, fcb, out);
}